// Round 11
// baseline (222.916 us; speedup 1.0000x reference)
//
#include <hip/hip_runtime.h>
#include <hip/hip_bf16.h>

// Problem constants
#define BB 8
#define NN 1024
#define CC 544      // J*F = 17*32
#define JJ 17
#define FF 32
#define HH 8
#define HD 68
#define BN 8192     // B*N
#define KD 544      // GEMM K dim (=C)
#define NCQ 1632    // 3*C
#define NCQP 1664   // padded to 13*128
#define NCPP 640    // proj out padded to 5*128
#define NKB 9       // k-blocks (8 dims each) stored for Q/K: 72 dims; 68 valid
#define BHSZ 73728  // elements per (b,h) Q/K slab: NKB*1024*8
#define AQR 64      // q-rows per attention block (2 waves x 2 groups x 16)

using f32x4  = __attribute__((ext_vector_type(4))) float;
using bf16x8 = __attribute__((ext_vector_type(8))) short;

__device__ __forceinline__ void gld_lds16(const void* g, void* l) {
  __builtin_amdgcn_global_load_lds(
      (const __attribute__((address_space(1))) void*)g,
      (__attribute__((address_space(3))) void*)l, 16, 0, 0);
}

// ---------------------------------------------------------------- K0: weights -> bf16 (padded) + zero Qp/Kp kblk-8 pad halves
__global__ __launch_bounds__(256) void wconv(const float* __restrict__ qkv_w,
                                             const float* __restrict__ proj_w,
                                             __hip_bfloat16* __restrict__ qw,
                                             __hip_bfloat16* __restrict__ pw,
                                             char* __restrict__ qkp) {
  int bid = blockIdx.x, t = threadIdx.x;
  if (bid < NCQP + NCPP) {
    bool isq = bid < NCQP;
    int r = isq ? bid : bid - NCQP;
    const float* src = isq ? qkv_w : proj_w;
    __hip_bfloat16* dst = isq ? qw : pw;
    int nrows = isq ? NCQ : CC;
    if (t < KD / 4) {
      int c = t * 4;
      float4 v;
      if (r < nrows) v = *(const float4*)(src + (size_t)r * KD + c);
      else           v = float4{0.f, 0.f, 0.f, 0.f};
      __hip_bfloat16 o[4] = {__float2bfloat16(v.x), __float2bfloat16(v.y),
                             __float2bfloat16(v.z), __float2bfloat16(v.w)};
      *(unsigned long long*)(dst + (size_t)r * KD + c) = *(unsigned long long*)o;
    }
  } else {
    int row = (bid - (NCQP + NCPP)) * 256 + t;  // 131072 = 128 bh-tensors x 1024 n
    if (row < 131072) {
      int bhT = row >> 10, n = row & 1023;
      // byte offset: bhT slabs of 147456B; kblk 8 at +131072B; n*16B; high 8B
      char* p = qkp + (size_t)bhT * 147456 + 131072 + (size_t)n * 16 + 8;
      *(unsigned long long*)p = 0ull;
    }
  }
}

// ---------------------------------------------------------------- K1: per-joint LN + attention-pool scores (xr -> bf16)
__global__ __launch_bounds__(256) void ln1_scores(const float* __restrict__ x,
                                                  const float* __restrict__ g,
                                                  const float* __restrict__ bta,
                                                  const float* __restrict__ apw,
                                                  const float* __restrict__ apb,
                                                  __hip_bfloat16* __restrict__ xr,
                                                  float* __restrict__ scores) {
  int wv = threadIdx.x >> 6, lane = threadIdx.x & 63;
  int bn = blockIdx.x * 4 + wv;
  int f = lane & 31, half = lane >> 5;
  const float* row = x + (size_t)bn * CC;
  float gg = g[f], bb = bta[f], aw = apw[f], ab = apb[0];
  for (int it = 0; it < 9; ++it) {
    int j = it * 2 + half;
    bool act = (j < JJ);
    float v = act ? row[j * FF + f] : 0.f;
    float s = v;
    for (int m = 16; m >= 1; m >>= 1) s += __shfl_xor(s, m);
    float mu = s * (1.f / 32.f);
    float dv = v - mu;
    float s2 = dv * dv;
    for (int m = 16; m >= 1; m >>= 1) s2 += __shfl_xor(s2, m);
    float xn = dv * rsqrtf(s2 * (1.f / 32.f) + 1e-5f) * gg + bb;
    float sc = xn * aw;
    for (int m = 16; m >= 1; m >>= 1) sc += __shfl_xor(sc, m);
    if (act) {
      xr[(size_t)bn * CC + j * FF + f] = __float2bfloat16(xn);
      if (f == 0) scores[bn * JJ + j] = sc + ab;
    }
  }
}

// ---------------------------------------------------------------- K2: per-(b,j) softmax stats over N -> {max, 1/sum}
__global__ __launch_bounds__(256) void softmax_red(const float* __restrict__ scores,
                                                   float2* __restrict__ tab) {
  int bj = blockIdx.x;
  int b = bj / JJ, j = bj - b * JJ;
  const float* s = scores + (size_t)b * NN * JJ + j;
  int t = threadIdx.x;
  float v[4];
  float mx = -1e30f;
#pragma unroll
  for (int i = 0; i < 4; ++i) { v[i] = s[(t + 256 * i) * JJ]; mx = fmaxf(mx, v[i]); }
#pragma unroll
  for (int m = 32; m >= 1; m >>= 1) mx = fmaxf(mx, __shfl_xor(mx, m));
  __shared__ float red[4];
  if ((t & 63) == 0) red[t >> 6] = mx;
  __syncthreads();
  mx = fmaxf(fmaxf(red[0], red[1]), fmaxf(red[2], red[3]));
  float sum = 0.f;
#pragma unroll
  for (int i = 0; i < 4; ++i) sum += __expf(v[i] - mx);
#pragma unroll
  for (int m = 32; m >= 1; m >>= 1) sum += __shfl_xor(sum, m);
  __shared__ float red2[4];
  if ((t & 63) == 0) red2[t >> 6] = sum;
  __syncthreads();
  if (t == 0) {
    sum = red2[0] + red2[1] + red2[2] + red2[3];
    tab[bj] = make_float2(mx, 1.f / sum);
  }
}

// ---------------------------------------------------------------- K3: xp = xr*w (w recomputed from scores+tab), LN2, -> bf16
__global__ __launch_bounds__(256) void ln2_xp(const __hip_bfloat16* __restrict__ xr,
                                              const float* __restrict__ scores,
                                              const float2* __restrict__ tab,
                                              const float* __restrict__ g2,
                                              const float* __restrict__ b2,
                                              __hip_bfloat16* __restrict__ xp) {
  __shared__ float wsh[4][JJ];
  int wv = threadIdx.x >> 6, lane = threadIdx.x & 63;
  int bn = blockIdx.x * 4 + wv;
  if (lane < JJ) {
    float sc = scores[bn * JJ + lane];
    float2 mi = tab[(bn >> 10) * JJ + lane];
    wsh[wv][lane] = __expf(sc - mi.x) * mi.y;
  }
  // same-wave producer/consumer: lgkmcnt ordering suffices, no __syncthreads
  float vals[9];
  float sum = 0.f;
  for (int it = 0; it < 9; ++it) {
    int c = it * 64 + lane;
    float v = 0.f;
    if (c < CC) v = __bfloat162float(xr[(size_t)bn * CC + c]) * wsh[wv][c >> 5];
    vals[it] = v;
    sum += v;
  }
  for (int m = 32; m >= 1; m >>= 1) sum += __shfl_xor(sum, m);
  float mu = sum * (1.f / 544.f);
  float s2 = 0.f;
  for (int it = 0; it < 9; ++it) {
    int c = it * 64 + lane;
    if (c < CC) { float dv = vals[it] - mu; s2 += dv * dv; }
  }
  for (int m = 32; m >= 1; m >>= 1) s2 += __shfl_xor(s2, m);
  float rstd = rsqrtf(s2 * (1.f / 544.f) + 1e-5f);
  for (int it = 0; it < 9; ++it) {
    int c = it * 64 + lane;
    if (c < CC)
      xp[(size_t)bn * CC + c] = __float2bfloat16((vals[it] - mu) * rstd * g2[c] + b2[c]);
  }
}

// ---------------------------------------------------------------- GEMM: C[M,N] = A[M,K] * B[N,K]^T, bf16 MFMA
// R19 (kept): MODE 0 epilogue routes Q/K/V through the freed As/Bs LDS and
// emits layout-exact WIDE stores (Q/K 8B packets, V 16B segments).
template <int MODE>
__global__ __launch_bounds__(256) void gemm_nt(const __hip_bfloat16* __restrict__ A,
                                               const __hip_bfloat16* __restrict__ Bw,
                                               __hip_bfloat16* __restrict__ Qp,
                                               __hip_bfloat16* __restrict__ Kp,
                                               __hip_bfloat16* __restrict__ Vt,
                                               float* __restrict__ Cf,
                                               const float* __restrict__ bias,
                                               const float* __restrict__ sfp) {
  extern __shared__ char smem[];  // 34816B: K-loop = As[2]|Bs[2] (32KB); MODE0 epilogue = Cst[128][136] bf16
  __hip_bfloat16 (*As)[128 * 32] = (__hip_bfloat16 (*)[128 * 32])(smem);
  __hip_bfloat16 (*Bs)[128 * 32] = (__hip_bfloat16 (*)[128 * 32])(smem + 16384);
  const int t = threadIdx.x;
  const int w = t >> 6, lane = t & 63;
  const int fr = lane & 15, fq = lane >> 4;
  const int bi = blockIdx.x;
  const int xcd = bi & 7, j = bi >> 3;
  const int bx = xcd * 8 + (j & 7), by = j >> 3;
  const int m0 = bx * 128;
  const int n0 = by * 128;
  const int wm = (w >> 1) * 64, wn = (w & 1) * 64;

  f32x4 acc[4][4] = {};

  const __hip_bfloat16* Ag = A + (size_t)m0 * KD;
  const __hip_bfloat16* Bg = Bw + (size_t)n0 * KD;

#pragma unroll
  for (int i2 = 0; i2 < 2; ++i2) {
    int cb = (i2 * 4 + w) * 64;
    int chunk = cb + lane;
    int row = chunk >> 2, c16 = chunk & 3;
    gld_lds16(Ag + (size_t)row * KD + c16 * 8, &As[0][cb * 8]);
    gld_lds16(Bg + (size_t)row * KD + c16 * 8, &Bs[0][cb * 8]);
  }
  __syncthreads();

  for (int kt = 0; kt < 17; ++kt) {
    const int cur = kt & 1;
    if (kt < 16) {
      const int k0 = (kt + 1) * 32;
#pragma unroll
      for (int i2 = 0; i2 < 2; ++i2) {
        int cb = (i2 * 4 + w) * 64;
        int chunk = cb + lane;
        int row = chunk >> 2, c16 = chunk & 3;
        gld_lds16(Ag + (size_t)row * KD + k0 + c16 * 8, &As[1 - cur][cb * 8]);
        gld_lds16(Bg + (size_t)row * KD + k0 + c16 * 8, &Bs[1 - cur][cb * 8]);
      }
    }
    bf16x8 af[4], bfr[4];
#pragma unroll
    for (int tm = 0; tm < 4; ++tm)
      af[tm] = *(const bf16x8*)&As[cur][(wm + tm * 16 + fr) * 32 + fq * 8];
#pragma unroll
    for (int tn = 0; tn < 4; ++tn)
      bfr[tn] = *(const bf16x8*)&Bs[cur][(wn + tn * 16 + fr) * 32 + fq * 8];
#pragma unroll
    for (int tm = 0; tm < 4; ++tm)
#pragma unroll
      for (int tn = 0; tn < 4; ++tn)
        acc[tm][tn] = __builtin_amdgcn_mfma_f32_16x16x32_bf16(af[tm], bfr[tn], acc[tm][tn], 0, 0, 0);
    __syncthreads();  // cur reads done; drains kt+1 prefetch (hidden behind MFMAs)
  }

  if (MODE == 1) {
#pragma unroll
    for (int tn = 0; tn < 4; ++tn) {
      int o = n0 + wn + tn * 16 + fr;
      if (o < CC) {
        float bb = bias[o];
#pragma unroll
        for (int tm = 0; tm < 4; ++tm) {
          int m = m0 + wm + tm * 16 + fq * 4;
#pragma unroll
          for (int r = 0; r < 4; ++r)
            Cf[(size_t)(m + r) * CC + o] = acc[tm][tn][r] + bb;
        }
      }
    }
  } else {
    const int b = m0 >> 10;
    const int nbase = m0 & (NN - 1);
    const float sf = sfp[0];
    __hip_bfloat16* Cst = (__hip_bfloat16*)smem;  // [128 o][136 m]; rows 272B (16B-aligned)

    // ---- stage the 128x128 tile into LDS (K pos-scale folded here)
#pragma unroll
    for (int tn = 0; tn < 4; ++tn) {
      int olocal = wn + tn * 16 + fr;
      int o = n0 + olocal;
      bool isk = (o >= CC) && (o < 2 * CC);
#pragma unroll
      for (int tm = 0; tm < 4; ++tm) {
        int mloc = wm + tm * 16 + fq * 4;
        int n = nbase + mloc;
#pragma unroll
        for (int r = 0; r < 4; ++r) {
          float v = acc[tm][tn][r];
          if (isk) {
            float pos = (n + r) * (1.f / 1023.f) - 0.5f;
            v *= __expf(-sf * pos * pos) * (0.12126781251816650f * 1.44269504088896340f);
          }
          Cst[olocal * 136 + mloc + r] = __float2bfloat16(v);
        }
      }
    }
    __syncthreads();

    // ---- Q/K: 8B stores; 4-dim groups (q/k and head boundaries are 4-aligned)
    for (int s = t; s < 32 * 128; s += 256) {
      int g = s >> 7, nl = s & 127;
      int o = n0 + g * 4;
      if (o < 2 * CC) {
        bool isk = o >= CC;
        int oo = isk ? o - CC : o;
        int h = oo / HD;
        int d0 = oo - h * HD;  // 4-aligned; d0&7 in {0,4}; d0>>3 uniform over the group
        unsigned long long pk;
        __hip_bfloat16* pp = (__hip_bfloat16*)&pk;
#pragma unroll
        for (int j2 = 0; j2 < 4; ++j2) pp[j2] = Cst[(g * 4 + j2) * 136 + nl];
        __hip_bfloat16* basep = isk ? Kp : Qp;
        size_t ei = (size_t)(b * HH + h) * BHSZ + (size_t)(d0 >> 3) * (NN * 8) +
                    (size_t)(nbase + nl) * 8 + (d0 & 7);
        *(unsigned long long*)(basep + ei) = pk;
      }
    }
    // ---- V: 16B row-segment stores (Vt is d-major; each Cst o-row is one d-row)
    {
      int lo = 2 * CC - n0; if (lo < 0) lo = 0;   // first V o_local
      int hi = NCQ - n0;    if (hi > 128) hi = 128;  // end o_local (pad excluded)
      if (hi > lo) {
        int nv = hi - lo;
        for (int s = t; s < nv * 16; s += 256) {
          int row = lo + (s >> 4), seg = s & 15;
          int oo = n0 + row - 2 * CC;
          int h = oo / HD;
          int d = oo - h * HD;
          bf16x8 v8 = *(const bf16x8*)&Cst[row * 136 + seg * 8];
          __hip_bfloat16* vdst = Vt + ((size_t)(b * HH + h) * HD + d) * NN + nbase + seg * 8;
          *(bf16x8*)vdst = v8;
        }
      }
    }
  }
}

// ---------------------------------------------------------------- Flash attention (R20b: resubmit of R20 after infra-failed
// bench — audited: zero barriers (nothing to deadlock), all addresses in-bounds, macro body = R18's compiled code)
// R18 retry with the spill cause removed. R18's failure signature (VGPR
// exactly 128 + 13MB scratch traffic) was NOT a register-budget violation
// (lb(128,2) permits 256; kernel needs ~244): the lambda taking kfA/kfB as
// REFERENCE parameters forced the arrays to memory (rule #20 family), and
// regalloc then targeted the 128-reg step. Fix: macro-inline the phase body
// so kfA/kfB are only ever statically-indexed named arrays, and lb(128,1)
// so the allocator is free up to the 2-waves/SIMD register budget (grid
// 1024 x 2 waves stays fully resident if VGPR <= 256).
// Structure = R17 (passed): barrier-free, Q/K/V all register-resident,
// wave-private P LDS. K(kt+1) loads issue at phase top, consumed next phase.
__global__ __launch_bounds__(128, 1) void attn_kernel(const __hip_bfloat16* __restrict__ Qp,
                                                      const __hip_bfloat16* __restrict__ Kp,
                                                      const __hip_bfloat16* __restrict__ Vt,
                                                      __hip_bfloat16* __restrict__ Ao) {
  __shared__ __hip_bfloat16 Ps[4 * 1152];  // 9216B: per wave-group 16x72 P scratch (wave-private)
  const int t = threadIdx.x;
  const int w = t >> 6, lane = t & 63;
  const int fr = lane & 15, fq = lane >> 4;
  const int idx = blockIdx.x;
  const int bh = idx & 63, qt = idx >> 6;
  const int h = bh & 7, b = bh >> 3;

  const __hip_bfloat16* qbase = Qp + (size_t)bh * BHSZ;
  const __hip_bfloat16* kbase = Kp + (size_t)bh * BHSZ;
  const __hip_bfloat16* vbase = Vt + (size_t)bh * HD * NN;

  const bf16x8 zero8 = {};

  // ---- prologue: Q fragments straight to registers (kblk = ks*4+fq; 9..11 virtual zero)
  bf16x8 qa[2][3];
#pragma unroll
  for (int ks = 0; ks < 3; ++ks) {
    int kblk = ks * 4 + fq;
    int kbc = kblk > 8 ? 8 : kblk;  // clamp; clamped lanes overwritten by zero
#pragma unroll
    for (int g = 0; g < 2; ++g) {
      bf16x8 v = *(const bf16x8*)(qbase + (size_t)kbc * (NN * 8) +
                                  ((size_t)qt * AQR + w * 32 + g * 16 + fr) * 8);
      if (kblk > 8) v = zero8;
      qa[g][ks] = v;
    }
  }

  f32x4 o_acc[2][5] = {};
  float l_part[2][4] = {};
  const int dclamp = (fr < 4) ? 0 : 1;  // tv=4 rows 64+fr valid only for fr<4

// ---- K tile loader into a NAMED static array (12 x bf16x8, per-lane 16B coalesced)
#define LDK(KN, KTN)                                                                   \
  {                                                                                    \
    _Pragma("unroll") for (int ks = 0; ks < 3; ++ks) {                                 \
      int kblk = ks * 4 + fq;                                                          \
      int kbc = kblk > 8 ? 8 : kblk;                                                   \
      const __hip_bfloat16* kp0 =                                                      \
          kbase + (size_t)kbc * (NN * 8) + ((size_t)(KTN) * 64 + fr) * 8;              \
      _Pragma("unroll") for (int tn = 0; tn < 4; ++tn) {                               \
        bf16x8 v = *(const bf16x8*)(kp0 + tn * 128);                                   \
        if (kblk > 8) v = zero8;                                                       \
        KN[ks][tn] = v;                                                                \
      }                                                                                \
    }                                                                                  \
  }

// ---- one pipeline phase: compute tile KT from KC; prefetch tile (KT+1)&15 into KN
#define PHASE(KC, KN, KT)                                                              \
  {                                                                                    \
    bf16x8 vfrag[5][2];                                                                \
    _Pragma("unroll") for (int tv = 0; tv < 5; ++tv) {                                 \
      int d = tv * 16 + fr;                                                            \
      int dc = (tv == 4 && dclamp) ? 0 : d;                                            \
      _Pragma("unroll") for (int ks2 = 0; ks2 < 2; ++ks2)                              \
          vfrag[tv][ks2] =                                                             \
          *(const bf16x8*)(vbase + (size_t)dc * NN + (KT) * 64 + ks2 * 32 + fq * 8);   \
    }                                                                                  \
    LDK(KN, ((KT) + 1) & 15);                                                          \
    _Pragma("unroll") for (int g = 0; g < 2; ++g) {                                    \
      f32x4 s[4] = {};                                                                 \
      _Pragma("unroll") for (int ks = 0; ks < 3; ++ks)                                 \
          _Pragma("unroll") for (int tn = 0; tn < 4; ++tn)                             \
              s[tn] = __builtin_amdgcn_mfma_f32_16x16x32_bf16(qa[g][ks], KC[ks][tn],   \
                                                              s[tn], 0, 0, 0);         \
      __hip_bfloat16* Pw = &Ps[(w * 2 + g) * 1152];                                    \
      _Pragma("unroll") for (int tn = 0; tn < 4; ++tn)                                 \
          _Pragma("unroll") for (int r = 0; r < 4; ++r) {                              \
        float pe = __builtin_amdgcn_exp2f(s[tn][r]);                                   \
        l_part[g][r] += pe;                                                            \
        Pw[(fq * 4 + r) * 72 + tn * 16 + fr] = __float2bfloat16(pe);                   \
      }                                                                                \
    }                                                                                  \
    _Pragma("unroll") for (int ks2 = 0; ks2 < 2; ++ks2) {                              \
      bf16x8 pa0 = *(const bf16x8*)&Ps[(w * 2 + 0) * 1152 + fr * 72 + ks2 * 32 + fq * 8]; \
      bf16x8 pa1 = *(const bf16x8*)&Ps[(w * 2 + 1) * 1152 + fr * 72 + ks2 * 32 + fq * 8]; \
      _Pragma("unroll") for (int tv = 0; tv < 5; ++tv) {                               \
        o_acc[0][tv] = __builtin_amdgcn_mfma_f32_16x16x32_bf16(pa0, vfrag[tv][ks2],    \
                                                               o_acc[0][tv], 0, 0, 0); \
        o_acc[1][tv] = __builtin_amdgcn_mfma_f32_16x16x32_bf16(pa1, vfrag[tv][ks2],    \
                                                               o_acc[1][tv], 0, 0, 0); \
      }                                                                                \
    }                                                                                  \
  }

  // ---- main loop: 2-phase static software pipeline (kfA/kfB named buffers, no lambdas)
  bf16x8 kfA[3][4], kfB[3][4];
  LDK(kfA, 0);
  for (int kt = 0; kt < 16; kt += 2) {
    PHASE(kfA, kfB, kt);      // compute kt (kfA), prefetch kt+1 -> kfB
    PHASE(kfB, kfA, kt + 1);  // compute kt+1 (kfB), prefetch kt+2 -> kfA
  }
#undef PHASE
#undef LDK

  // ---- epilogue: reduce l across the 16 row-lanes (4 shfls, once), O / l -> bf16
#pragma unroll
  for (int g = 0; g < 2; ++g) {
    __hip_bfloat16* obase = Ao + (size_t)(b * NN + qt * AQR + w * 32 + g * 16) * CC + h * HD;
    float inv[4];
#pragma unroll
    for (int r = 0; r < 4; ++r) {
      float l = l_part[g][r];
#pragma unroll
      for (int msk = 8; msk >= 1; msk >>= 1) l += __shfl_xor(l, msk);
      inv[r] = 1.f / l;
    }
#pragma unroll
    for (int tv = 0; tv < 5; ++tv) {
      int d = tv * 16 + fr;
      if (d < HD) {
#pragma unroll
        for (int r = 0; r < 4; ++r)
          obase[(size_t)(fq * 4 + r) * CC + d] = __float2bfloat16(o_acc[g][tv][r] * inv[r]);
      }
    }
  }
}

// ---------------------------------------------------------------- launch
extern "C" void kernel_launch(void* const* d_in, const int* in_sizes, int n_in,
                              void* d_out, int out_size, void* d_ws, size_t ws_size,
                              hipStream_t stream) {
  (void)in_sizes; (void)n_in; (void)out_size; (void)ws_size;
  const float* x       = (const float*)d_in[0];
  const float* norm_g  = (const float*)d_in[1];
  const float* norm_b  = (const float*)d_in[2];
  const float* ap_w    = (const float*)d_in[3];
  const float* ap_b    = (const float*)d_in[4];
  const float* norm2_g = (const float*)d_in[5];
  const float* norm2_b = (const float*)d_in[6];
  const float* qkv_w   = (const float*)d_in[7];
  const float* proj_w  = (const float*)d_in[8];
  const float* proj_b  = (const float*)d_in[9];
  const float* sf      = (const float*)d_in[10];
  float* out = (float*)d_out;
  char* ws = (char*)d_ws;

  // workspace layout (bytes) — 57.6MB total (qp/kp: 9 kblk k-major slabs)
  __hip_bfloat16* xr   = (__hip_bfloat16*)(ws);                // 8192*544*2  = 8912896
  float* scores        = (float*)(ws + 8912896);               // 8192*17*4   = 557056
  float2* tab          = (float2*)(ws + 9469952);              // 136*8 -> pad 4096
  __hip_bfloat16* xp   = (__hip_bfloat16*)(ws + 9474048);      // 8912896
  __hip_bfloat16* qw   = (__hip_bfloat16*)(ws + 18386944);     // 1664*544*2  = 1810432
  __hip_bfloat16* pw   = (__hip_bfloat16*)(ws + 20197376);     // 640*544*2   = 696320
  __hip_bfloat16* vt   = (__hip_bfloat16*)(ws + 20893696);     // 8*8*68*1024*2 = 8912896
  __hip_bfloat16* ao   = (__hip_bfloat16*)(ws + 29806592);     // 8912896
  __hip_bfloat16* qp   = (__hip_bfloat16*)(ws + 38719488);     // 64*73728*2 = 9437184
  __hip_bfloat16* kp   = (__hip_bfloat16*)(ws + 48156672);     // 9437184 (contiguous after qp for wconv pad-zeroing)
  // total 57593856 bytes

  wconv<<<NCQP + NCPP + 512, 256, 0, stream>>>(qkv_w, proj_w, qw, pw, (char*)qp);
  ln1_scores<<<BN / 4, 256, 0, stream>>>(x, norm_g, norm_b, ap_w, ap_b, xr, scores);
  softmax_red<<<BB * JJ, 256, 0, stream>>>(scores, tab);
  ln2_xp<<<BN / 4, 256, 0, stream>>>(xr, scores, tab, norm2_g, norm2_b, xp);
  gemm_nt<0><<<dim3(64 * 13), 256, 34816, stream>>>(xp, qw, qp, kp, vt, nullptr, nullptr, sf);
  attn_kernel<<<dim3((NN / AQR) * HH * BB), 128, 0, stream>>>(qp, kp, vt, ao);
  gemm_nt<1><<<dim3(64 * 5), 256, 34816, stream>>>(ao, pw, nullptr, nullptr, nullptr, out, proj_b, nullptr);
}

// Round 12
// 200.043 us; speedup vs baseline: 1.1143x; 1.1143x over previous
//
#include <hip/hip_runtime.h>
#include <hip/hip_bf16.h>

// Problem constants
#define BB 8
#define NN 1024
#define CC 544      // J*F = 17*32
#define JJ 17
#define FF 32
#define HH 8
#define HD 68
#define BN 8192     // B*N
#define KD 544      // GEMM K dim (=C)
#define NCQ 1632    // 3*C
#define NCQP 1664   // padded to 13*128
#define NCPP 640    // proj out padded to 5*128
#define NKB 9       // k-blocks (8 dims each) stored for Q/K: 72 dims; 68 valid
#define BHSZ 73728  // elements per (b,h) Q/K slab: NKB*1024*8
#define AQR 64      // q-rows per attention block (2 waves x 2 groups x 16)

using f32x4  = __attribute__((ext_vector_type(4))) float;
using bf16x8 = __attribute__((ext_vector_type(8))) short;

__device__ __forceinline__ void gld_lds16(const void* g, void* l) {
  __builtin_amdgcn_global_load_lds(
      (const __attribute__((address_space(1))) void*)g,
      (__attribute__((address_space(3))) void*)l, 16, 0, 0);
}

// ---------------------------------------------------------------- K0+K1 merged (R21): weight conversion + per-joint LN/scores
// The two are fully independent (disjoint inputs/outputs); merging removes one
// serial launch gap from the graph. bid < 2048 -> ln1 work; else wconv work.
__global__ __launch_bounds__(256) void wconv_ln1(const float* __restrict__ x,
                                                 const float* __restrict__ g,
                                                 const float* __restrict__ bta,
                                                 const float* __restrict__ apw,
                                                 const float* __restrict__ apb,
                                                 __hip_bfloat16* __restrict__ xr,
                                                 float* __restrict__ scores,
                                                 const float* __restrict__ qkv_w,
                                                 const float* __restrict__ proj_w,
                                                 __hip_bfloat16* __restrict__ qw,
                                                 __hip_bfloat16* __restrict__ pw,
                                                 char* __restrict__ qkp) {
  int bid = blockIdx.x, t = threadIdx.x;
  if (bid < BN / 4) {
    // ---- ln1_scores body (4 waves = 4 tokens per block)
    int wv = t >> 6, lane = t & 63;
    int bn = bid * 4 + wv;
    int f = lane & 31, half = lane >> 5;
    const float* row = x + (size_t)bn * CC;
    float gg = g[f], bb = bta[f], aw = apw[f], ab = apb[0];
    for (int it = 0; it < 9; ++it) {
      int j = it * 2 + half;
      bool act = (j < JJ);
      float v = act ? row[j * FF + f] : 0.f;
      float s = v;
      for (int m = 16; m >= 1; m >>= 1) s += __shfl_xor(s, m);
      float mu = s * (1.f / 32.f);
      float dv = v - mu;
      float s2 = dv * dv;
      for (int m = 16; m >= 1; m >>= 1) s2 += __shfl_xor(s2, m);
      float xn = dv * rsqrtf(s2 * (1.f / 32.f) + 1e-5f) * gg + bb;
      float sc = xn * aw;
      for (int m = 16; m >= 1; m >>= 1) sc += __shfl_xor(sc, m);
      if (act) {
        xr[(size_t)bn * CC + j * FF + f] = __float2bfloat16(xn);
        if (f == 0) scores[bn * JJ + j] = sc + ab;
      }
    }
  } else {
    // ---- wconv body (weights -> bf16 padded; zero Qp/Kp kblk-8 pad halves)
    int wb = bid - BN / 4;
    if (wb < NCQP + NCPP) {
      bool isq = wb < NCQP;
      int r = isq ? wb : wb - NCQP;
      const float* src = isq ? qkv_w : proj_w;
      __hip_bfloat16* dst = isq ? qw : pw;
      int nrows = isq ? NCQ : CC;
      if (t < KD / 4) {
        int c = t * 4;
        float4 v;
        if (r < nrows) v = *(const float4*)(src + (size_t)r * KD + c);
        else           v = float4{0.f, 0.f, 0.f, 0.f};
        __hip_bfloat16 o[4] = {__float2bfloat16(v.x), __float2bfloat16(v.y),
                               __float2bfloat16(v.z), __float2bfloat16(v.w)};
        *(unsigned long long*)(dst + (size_t)r * KD + c) = *(unsigned long long*)o;
      }
    } else {
      int row = (wb - (NCQP + NCPP)) * 256 + t;  // 131072 = 128 bh-tensors x 1024 n
      if (row < 131072) {
        int bhT = row >> 10, n = row & 1023;
        // byte offset: bhT slabs of 147456B; kblk 8 at +131072B; n*16B; high 8B
        char* p = qkp + (size_t)bhT * 147456 + 131072 + (size_t)n * 16 + 8;
        *(unsigned long long*)p = 0ull;
      }
    }
  }
}

// ---------------------------------------------------------------- K2: per-(b,j) softmax stats over N -> {max, 1/sum}
__global__ __launch_bounds__(256) void softmax_red(const float* __restrict__ scores,
                                                   float2* __restrict__ tab) {
  int bj = blockIdx.x;
  int b = bj / JJ, j = bj - b * JJ;
  const float* s = scores + (size_t)b * NN * JJ + j;
  int t = threadIdx.x;
  float v[4];
  float mx = -1e30f;
#pragma unroll
  for (int i = 0; i < 4; ++i) { v[i] = s[(t + 256 * i) * JJ]; mx = fmaxf(mx, v[i]); }
#pragma unroll
  for (int m = 32; m >= 1; m >>= 1) mx = fmaxf(mx, __shfl_xor(mx, m));
  __shared__ float red[4];
  if ((t & 63) == 0) red[t >> 6] = mx;
  __syncthreads();
  mx = fmaxf(fmaxf(red[0], red[1]), fmaxf(red[2], red[3]));
  float sum = 0.f;
#pragma unroll
  for (int i = 0; i < 4; ++i) sum += __expf(v[i] - mx);
#pragma unroll
  for (int m = 32; m >= 1; m >>= 1) sum += __shfl_xor(sum, m);
  __shared__ float red2[4];
  if ((t & 63) == 0) red2[t >> 6] = sum;
  __syncthreads();
  if (t == 0) {
    sum = red2[0] + red2[1] + red2[2] + red2[3];
    tab[bj] = make_float2(mx, 1.f / sum);
  }
}

// ---------------------------------------------------------------- K3: xp = xr*w (w recomputed from scores+tab), LN2, -> bf16
__global__ __launch_bounds__(256) void ln2_xp(const __hip_bfloat16* __restrict__ xr,
                                              const float* __restrict__ scores,
                                              const float2* __restrict__ tab,
                                              const float* __restrict__ g2,
                                              const float* __restrict__ b2,
                                              __hip_bfloat16* __restrict__ xp) {
  __shared__ float wsh[4][JJ];
  int wv = threadIdx.x >> 6, lane = threadIdx.x & 63;
  int bn = blockIdx.x * 4 + wv;
  if (lane < JJ) {
    float sc = scores[bn * JJ + lane];
    float2 mi = tab[(bn >> 10) * JJ + lane];
    wsh[wv][lane] = __expf(sc - mi.x) * mi.y;
  }
  // same-wave producer/consumer: lgkmcnt ordering suffices, no __syncthreads
  float vals[9];
  float sum = 0.f;
  for (int it = 0; it < 9; ++it) {
    int c = it * 64 + lane;
    float v = 0.f;
    if (c < CC) v = __bfloat162float(xr[(size_t)bn * CC + c]) * wsh[wv][c >> 5];
    vals[it] = v;
    sum += v;
  }
  for (int m = 32; m >= 1; m >>= 1) sum += __shfl_xor(sum, m);
  float mu = sum * (1.f / 544.f);
  float s2 = 0.f;
  for (int it = 0; it < 9; ++it) {
    int c = it * 64 + lane;
    if (c < CC) { float dv = vals[it] - mu; s2 += dv * dv; }
  }
  for (int m = 32; m >= 1; m >>= 1) s2 += __shfl_xor(s2, m);
  float rstd = rsqrtf(s2 * (1.f / 544.f) + 1e-5f);
  for (int it = 0; it < 9; ++it) {
    int c = it * 64 + lane;
    if (c < CC)
      xp[(size_t)bn * CC + c] = __float2bfloat16((vals[it] - mu) * rstd * g2[c] + b2[c]);
  }
}

// ---------------------------------------------------------------- GEMM: C[M,N] = A[M,K] * B[N,K]^T, bf16 MFMA
// R19 (kept): MODE 0 epilogue routes Q/K/V through the freed As/Bs LDS and
// emits layout-exact WIDE stores (Q/K 8B packets, V 16B segments).
template <int MODE>
__global__ __launch_bounds__(256) void gemm_nt(const __hip_bfloat16* __restrict__ A,
                                               const __hip_bfloat16* __restrict__ Bw,
                                               __hip_bfloat16* __restrict__ Qp,
                                               __hip_bfloat16* __restrict__ Kp,
                                               __hip_bfloat16* __restrict__ Vt,
                                               float* __restrict__ Cf,
                                               const float* __restrict__ bias,
                                               const float* __restrict__ sfp) {
  extern __shared__ char smem[];  // 34816B: K-loop = As[2]|Bs[2] (32KB); MODE0 epilogue = Cst[128][136] bf16
  __hip_bfloat16 (*As)[128 * 32] = (__hip_bfloat16 (*)[128 * 32])(smem);
  __hip_bfloat16 (*Bs)[128 * 32] = (__hip_bfloat16 (*)[128 * 32])(smem + 16384);
  const int t = threadIdx.x;
  const int w = t >> 6, lane = t & 63;
  const int fr = lane & 15, fq = lane >> 4;
  const int bi = blockIdx.x;
  const int xcd = bi & 7, j = bi >> 3;
  const int bx = xcd * 8 + (j & 7), by = j >> 3;
  const int m0 = bx * 128;
  const int n0 = by * 128;
  const int wm = (w >> 1) * 64, wn = (w & 1) * 64;

  f32x4 acc[4][4] = {};

  const __hip_bfloat16* Ag = A + (size_t)m0 * KD;
  const __hip_bfloat16* Bg = Bw + (size_t)n0 * KD;

#pragma unroll
  for (int i2 = 0; i2 < 2; ++i2) {
    int cb = (i2 * 4 + w) * 64;
    int chunk = cb + lane;
    int row = chunk >> 2, c16 = chunk & 3;
    gld_lds16(Ag + (size_t)row * KD + c16 * 8, &As[0][cb * 8]);
    gld_lds16(Bg + (size_t)row * KD + c16 * 8, &Bs[0][cb * 8]);
  }
  __syncthreads();

  for (int kt = 0; kt < 17; ++kt) {
    const int cur = kt & 1;
    if (kt < 16) {
      const int k0 = (kt + 1) * 32;
#pragma unroll
      for (int i2 = 0; i2 < 2; ++i2) {
        int cb = (i2 * 4 + w) * 64;
        int chunk = cb + lane;
        int row = chunk >> 2, c16 = chunk & 3;
        gld_lds16(Ag + (size_t)row * KD + k0 + c16 * 8, &As[1 - cur][cb * 8]);
        gld_lds16(Bg + (size_t)row * KD + k0 + c16 * 8, &Bs[1 - cur][cb * 8]);
      }
    }
    bf16x8 af[4], bfr[4];
#pragma unroll
    for (int tm = 0; tm < 4; ++tm)
      af[tm] = *(const bf16x8*)&As[cur][(wm + tm * 16 + fr) * 32 + fq * 8];
#pragma unroll
    for (int tn = 0; tn < 4; ++tn)
      bfr[tn] = *(const bf16x8*)&Bs[cur][(wn + tn * 16 + fr) * 32 + fq * 8];
#pragma unroll
    for (int tm = 0; tm < 4; ++tm)
#pragma unroll
      for (int tn = 0; tn < 4; ++tn)
        acc[tm][tn] = __builtin_amdgcn_mfma_f32_16x16x32_bf16(af[tm], bfr[tn], acc[tm][tn], 0, 0, 0);
    __syncthreads();  // cur reads done; drains kt+1 prefetch (hidden behind MFMAs)
  }

  if (MODE == 1) {
#pragma unroll
    for (int tn = 0; tn < 4; ++tn) {
      int o = n0 + wn + tn * 16 + fr;
      if (o < CC) {
        float bb = bias[o];
#pragma unroll
        for (int tm = 0; tm < 4; ++tm) {
          int m = m0 + wm + tm * 16 + fq * 4;
#pragma unroll
          for (int r = 0; r < 4; ++r)
            Cf[(size_t)(m + r) * CC + o] = acc[tm][tn][r] + bb;
        }
      }
    }
  } else {
    const int b = m0 >> 10;
    const int nbase = m0 & (NN - 1);
    const float sf = sfp[0];
    __hip_bfloat16* Cst = (__hip_bfloat16*)smem;  // [128 o][136 m]; rows 272B (16B-aligned)

    // ---- stage the 128x128 tile into LDS (K pos-scale folded here)
#pragma unroll
    for (int tn = 0; tn < 4; ++tn) {
      int olocal = wn + tn * 16 + fr;
      int o = n0 + olocal;
      bool isk = (o >= CC) && (o < 2 * CC);
#pragma unroll
      for (int tm = 0; tm < 4; ++tm) {
        int mloc = wm + tm * 16 + fq * 4;
        int n = nbase + mloc;
#pragma unroll
        for (int r = 0; r < 4; ++r) {
          float v = acc[tm][tn][r];
          if (isk) {
            float pos = (n + r) * (1.f / 1023.f) - 0.5f;
            v *= __expf(-sf * pos * pos) * (0.12126781251816650f * 1.44269504088896340f);
          }
          Cst[olocal * 136 + mloc + r] = __float2bfloat16(v);
        }
      }
    }
    __syncthreads();

    // ---- Q/K: 8B stores; 4-dim groups (q/k and head boundaries are 4-aligned)
    for (int s = t; s < 32 * 128; s += 256) {
      int g = s >> 7, nl = s & 127;
      int o = n0 + g * 4;
      if (o < 2 * CC) {
        bool isk = o >= CC;
        int oo = isk ? o - CC : o;
        int h = oo / HD;
        int d0 = oo - h * HD;  // 4-aligned; d0&7 in {0,4}; d0>>3 uniform over the group
        unsigned long long pk;
        __hip_bfloat16* pp = (__hip_bfloat16*)&pk;
#pragma unroll
        for (int j2 = 0; j2 < 4; ++j2) pp[j2] = Cst[(g * 4 + j2) * 136 + nl];
        __hip_bfloat16* basep = isk ? Kp : Qp;
        size_t ei = (size_t)(b * HH + h) * BHSZ + (size_t)(d0 >> 3) * (NN * 8) +
                    (size_t)(nbase + nl) * 8 + (d0 & 7);
        *(unsigned long long*)(basep + ei) = pk;
      }
    }
    // ---- V: 16B row-segment stores (Vt is d-major; each Cst o-row is one d-row)
    {
      int lo = 2 * CC - n0; if (lo < 0) lo = 0;   // first V o_local
      int hi = NCQ - n0;    if (hi > 128) hi = 128;  // end o_local (pad excluded)
      if (hi > lo) {
        int nv = hi - lo;
        for (int s = t; s < nv * 16; s += 256) {
          int row = lo + (s >> 4), seg = s & 15;
          int oo = n0 + row - 2 * CC;
          int h = oo / HD;
          int d = oo - h * HD;
          bf16x8 v8 = *(const bf16x8*)&Cst[row * 136 + seg * 8];
          __hip_bfloat16* vdst = Vt + ((size_t)(b * HH + h) * HD + d) * NN + nbase + seg * 8;
          *(bf16x8*)vdst = v8;
        }
      }
    }
  }
}

// ---------------------------------------------------------------- Flash attention (R21: R14 exact + setprio only)
// ATTN IS FROZEN at the R14 shape. Ten structural variants (R9/R12/R13:
// 4-wave; R15b: key-split; R16: counted-vmcnt; R17: barrier-free reg-K;
// R18/R20b: reg-pipelined K) all measured 55-98us vs this shape's 54us —
// the compiler will not hold a register prefetch (sinks/minimizes/spills/
// serializes it; R20b: VGPR 152, no spill, still 73us). Only addition vs
// R14: s_setprio(1/0) around the MFMA clusters — the one catalog technique
// measured attn-positive (m191, +4-7%), never tested in isolation here.
// R14's blocks are independent (4/CU at different phases) = setprio regime.
__global__ __launch_bounds__(128) void attn_kernel(const __hip_bfloat16* __restrict__ Qp,
                                                   const __hip_bfloat16* __restrict__ Kp,
                                                   const __hip_bfloat16* __restrict__ Vt,
                                                   __hip_bfloat16* __restrict__ Ao) {
  __shared__ __hip_bfloat16 Qs[NKB * 64 * 8];     // 9216B: Q staging; Ps[4][16][72] scratch in loop
  __shared__ __hip_bfloat16 Ks[2][NKB * 64 * 8];  // 2 x 9216B double buffer
  __shared__ __hip_bfloat16 Zs[64 * 8];           // 1024B zeros (virtual kblks 9..11)
  const int t = threadIdx.x;
  const int w = t >> 6, lane = t & 63;
  const int fr = lane & 15, fq = lane >> 4;
  const int idx = blockIdx.x;
  const int bh = idx & 63, qt = idx >> 6;
  const int h = bh & 7, b = bh >> 3;

  const __hip_bfloat16* qtile = Qp + (size_t)bh * BHSZ + (size_t)qt * AQR * 8;
  const __hip_bfloat16* kbase = Kp + (size_t)bh * BHSZ;
  const __hip_bfloat16* vbase = Vt + (size_t)bh * HD * NN;

  // ---- prologue: zero block; Q + K0 via DMA. k-major: inst kb loads 64 rows x 16B contiguous.
  *(unsigned long long*)&Zs[t * 4] = 0ull;
#pragma unroll
  for (int i = 0; i < 5; ++i) {
    int kb = i * 2 + w;  // wave-uniform kblk; wave0: 0,2,4,6,8  wave1: 1,3,5,7
    if (kb < NKB) gld_lds16(qtile + (size_t)kb * (NN * 8) + lane * 8, &Qs[kb * 64 * 8]);
  }
#pragma unroll
  for (int i = 0; i < 5; ++i) {
    int kb = i * 2 + w;
    if (kb < NKB) gld_lds16(kbase + (size_t)kb * (NN * 8) + lane * 8, &Ks[0][kb * 64 * 8]);
  }
  __syncthreads();  // drain Q + K0 DMA + Zs writes
  bf16x8 qa[2][3];
#pragma unroll
  for (int ks = 0; ks < 3; ++ks) {
    const __hip_bfloat16* qb = (ks < 2 || fq == 0) ? &Qs[(ks * 4 + fq) * 512] : Zs;
#pragma unroll
    for (int g = 0; g < 2; ++g)
      qa[g][ks] = *(const bf16x8*)&qb[(w * 32 + g * 16 + fr) * 8];
  }
  __syncthreads();  // all waves done reading Qs before it becomes Ps scratch

  f32x4 o_acc[2][5] = {};
  float l_part[2][4] = {};
  const int dclamp = (fr < 4) ? 0 : 1;  // tv=4 rows 64+fr valid only for fr<4

  for (int kt = 0; kt < 16; ++kt) {
    const int cur = kt & 1;
    // ---- V(kt) -> registers (issued first so the vfrag waitcnt leaves K DMA in flight)
    bf16x8 vfrag[5][2];
#pragma unroll
    for (int tv = 0; tv < 5; ++tv) {
      int d = tv * 16 + fr;
      int dc = (tv == 4 && dclamp) ? 0 : d;  // clamp OOB rows; outputs discarded
#pragma unroll
      for (int ks2 = 0; ks2 < 2; ++ks2)
        vfrag[tv][ks2] = *(const bf16x8*)(vbase + (size_t)dc * NN + kt * 64 + ks2 * 32 + fq * 8);
    }
    // ---- K(kt+1) DMA into the other buffer; drained at the END-of-tile barrier
    if (kt < 15) {
      const __hip_bfloat16* ktile = kbase + (size_t)(kt + 1) * 64 * 8;
#pragma unroll
      for (int i = 0; i < 5; ++i) {
        int kb = i * 2 + w;
        if (kb < NKB) gld_lds16(ktile + (size_t)kb * (NN * 8) + lane * 8, &Ks[1 - cur][kb * 64 * 8]);
      }
    }

    // ---- S = Q K^T for both row-groups; each K fragment load feeds 2 MFMAs
    f32x4 s[2][4] = {};
    __builtin_amdgcn_s_setprio(1);
#pragma unroll
    for (int ks = 0; ks < 3; ++ks) {
      const __hip_bfloat16* kbL = (ks < 2 || fq == 0) ? &Ks[cur][(ks * 4 + fq) * 512] : Zs;
#pragma unroll
      for (int tn = 0; tn < 4; ++tn) {
        bf16x8 kb = *(const bf16x8*)&kbL[(tn * 16 + fr) * 8];
        s[0][tn] = __builtin_amdgcn_mfma_f32_16x16x32_bf16(qa[0][ks], kb, s[0][tn], 0, 0, 0);
        s[1][tn] = __builtin_amdgcn_mfma_f32_16x16x32_bf16(qa[1][ks], kb, s[1][tn], 0, 0, 0);
      }
    }
    __builtin_amdgcn_s_setprio(0);
    // ---- no-max softmax: p = exp2(s) (log2e pre-folded into K); per-lane partial row sums
#pragma unroll
    for (int g = 0; g < 2; ++g) {
      __hip_bfloat16* Pw = &Qs[(w * 2 + g) * 1152];  // 16x72 per-wave-group region
#pragma unroll
      for (int tn = 0; tn < 4; ++tn)
#pragma unroll
        for (int r = 0; r < 4; ++r) {
          float pe = __builtin_amdgcn_exp2f(s[g][tn][r]);
          l_part[g][r] += pe;
          Pw[(fq * 4 + r) * 72 + tn * 16 + fr] = __float2bfloat16(pe);
        }
    }
    // ---- O += P V; V fragments from registers
    __builtin_amdgcn_s_setprio(1);
#pragma unroll
    for (int ks2 = 0; ks2 < 2; ++ks2) {
      bf16x8 pa0 = *(const bf16x8*)&Qs[(w * 2 + 0) * 1152 + fr * 72 + ks2 * 32 + fq * 8];
      bf16x8 pa1 = *(const bf16x8*)&Qs[(w * 2 + 1) * 1152 + fr * 72 + ks2 * 32 + fq * 8];
#pragma unroll
      for (int tv = 0; tv < 5; ++tv) {
        o_acc[0][tv] = __builtin_amdgcn_mfma_f32_16x16x32_bf16(pa0, vfrag[tv][ks2], o_acc[0][tv], 0, 0, 0);
        o_acc[1][tv] = __builtin_amdgcn_mfma_f32_16x16x32_bf16(pa1, vfrag[tv][ks2], o_acc[1][tv], 0, 0, 0);
      }
    }
    __builtin_amdgcn_s_setprio(0);
    __syncthreads();  // end of tile: Ks[cur]/Ps reads done; drains kt+1 prefetch (hidden)
  }
  // ---- epilogue: reduce l across the 16 row-lanes (4 shfls, once), O / l -> bf16
#pragma unroll
  for (int g = 0; g < 2; ++g) {
    __hip_bfloat16* obase = Ao + (size_t)(b * NN + qt * AQR + w * 32 + g * 16) * CC + h * HD;
    float inv[4];
#pragma unroll
    for (int r = 0; r < 4; ++r) {
      float l = l_part[g][r];
#pragma unroll
      for (int msk = 8; msk >= 1; msk >>= 1) l += __shfl_xor(l, msk);
      inv[r] = 1.f / l;
    }
#pragma unroll
    for (int tv = 0; tv < 5; ++tv) {
      int d = tv * 16 + fr;
      if (d < HD) {
#pragma unroll
        for (int r = 0; r < 4; ++r)
          obase[(size_t)(fq * 4 + r) * CC + d] = __float2bfloat16(o_acc[g][tv][r] * inv[r]);
      }
    }
  }
}

// ---------------------------------------------------------------- launch
extern "C" void kernel_launch(void* const* d_in, const int* in_sizes, int n_in,
                              void* d_out, int out_size, void* d_ws, size_t ws_size,
                              hipStream_t stream) {
  (void)in_sizes; (void)n_in; (void)out_size; (void)ws_size;
  const float* x       = (const float*)d_in[0];
  const float* norm_g  = (const float*)d_in[1];
  const float* norm_b  = (const float*)d_in[2];
  const float* ap_w    = (const float*)d_in[3];
  const float* ap_b    = (const float*)d_in[4];
  const float* norm2_g = (const float*)d_in[5];
  const float* norm2_b = (const float*)d_in[6];
  const float* qkv_w   = (const float*)d_in[7];
  const float* proj_w  = (const float*)d_in[8];
  const float* proj_b  = (const float*)d_in[9];
  const float* sf      = (const float*)d_in[10];
  float* out = (float*)d_out;
  char* ws = (char*)d_ws;

  // workspace layout (bytes) — 57.6MB total (qp/kp: 9 kblk k-major slabs)
  __hip_bfloat16* xr   = (__hip_bfloat16*)(ws);                // 8192*544*2  = 8912896
  float* scores        = (float*)(ws + 8912896);               // 8192*17*4   = 557056
  float2* tab          = (float2*)(ws + 9469952);              // 136*8 -> pad 4096
  __hip_bfloat16* xp   = (__hip_bfloat16*)(ws + 9474048);      // 8912896
  __hip_bfloat16* qw   = (__hip_bfloat16*)(ws + 18386944);     // 1664*544*2  = 1810432
  __hip_bfloat16* pw   = (__hip_bfloat16*)(ws + 20197376);     // 640*544*2   = 696320
  __hip_bfloat16* vt   = (__hip_bfloat16*)(ws + 20893696);     // 8*8*68*1024*2 = 8912896
  __hip_bfloat16* ao   = (__hip_bfloat16*)(ws + 29806592);     // 8912896
  __hip_bfloat16* qp   = (__hip_bfloat16*)(ws + 38719488);     // 64*73728*2 = 9437184
  __hip_bfloat16* kp   = (__hip_bfloat16*)(ws + 48156672);     // 9437184 (contiguous after qp for wconv pad-zeroing)
  // total 57593856 bytes

  wconv_ln1<<<BN / 4 + NCQP + NCPP + 512, 256, 0, stream>>>(
      x, norm_g, norm_b, ap_w, ap_b, xr, scores, qkv_w, proj_w, qw, pw, (char*)qp);
  softmax_red<<<BB * JJ, 256, 0, stream>>>(scores, tab);
  ln2_xp<<<BN / 4, 256, 0, stream>>>(xr, scores, tab, norm2_g, norm2_b, xp);
  gemm_nt<0><<<dim3(64 * 13), 256, 34816, stream>>>(xp, qw, qp, kp, vt, nullptr, nullptr, sf);
  attn_kernel<<<dim3((NN / AQR) * HH * BB), 128, 0, stream>>>(qp, kp, vt, ao);
  gemm_nt<1><<<dim3(64 * 5), 256, 34816, stream>>>(ao, pw, nullptr, nullptr, nullptr, out, proj_b, nullptr);
}

// Round 13
// 199.450 us; speedup vs baseline: 1.1177x; 1.0030x over previous
//
#include <hip/hip_runtime.h>
#include <hip/hip_bf16.h>

// Problem constants
#define BB 8
#define NN 1024
#define CC 544      // J*F = 17*32
#define JJ 17
#define FF 32
#define HH 8
#define HD 68
#define BN 8192     // B*N
#define KD 544      // GEMM K dim (=C)
#define NCQ 1632    // 3*C
#define NCQP 1664   // padded to 13*128
#define NCPP 640    // proj out padded to 5*128
#define NKB 9       // k-blocks (8 dims each) stored for Q/K: 72 dims; 68 valid
#define BHSZ 73728  // elements per (b,h) Q/K slab: NKB*1024*8
#define AQR 64      // q-rows per attention block (2 waves x 2 groups x 16)

using f32x4  = __attribute__((ext_vector_type(4))) float;
using bf16x8 = __attribute__((ext_vector_type(8))) short;

__device__ __forceinline__ void gld_lds16(const void* g, void* l) {
  __builtin_amdgcn_global_load_lds(
      (const __attribute__((address_space(1))) void*)g,
      (__attribute__((address_space(3))) void*)l, 16, 0, 0);
}

// ---------------------------------------------------------------- K0+K1 merged (R21, kept): weight conversion + LN1/scores
__global__ __launch_bounds__(256) void wconv_ln1(const float* __restrict__ x,
                                                 const float* __restrict__ g,
                                                 const float* __restrict__ bta,
                                                 const float* __restrict__ apw,
                                                 const float* __restrict__ apb,
                                                 __hip_bfloat16* __restrict__ xr,
                                                 float* __restrict__ scores,
                                                 const float* __restrict__ qkv_w,
                                                 const float* __restrict__ proj_w,
                                                 __hip_bfloat16* __restrict__ qw,
                                                 __hip_bfloat16* __restrict__ pw,
                                                 char* __restrict__ qkp) {
  int bid = blockIdx.x, t = threadIdx.x;
  if (bid < BN / 4) {
    // ---- ln1_scores body (4 waves = 4 tokens per block)
    int wv = t >> 6, lane = t & 63;
    int bn = bid * 4 + wv;
    int f = lane & 31, half = lane >> 5;
    const float* row = x + (size_t)bn * CC;
    float gg = g[f], bb = bta[f], aw = apw[f], ab = apb[0];
    for (int it = 0; it < 9; ++it) {
      int j = it * 2 + half;
      bool act = (j < JJ);
      float v = act ? row[j * FF + f] : 0.f;
      float s = v;
      for (int m = 16; m >= 1; m >>= 1) s += __shfl_xor(s, m);
      float mu = s * (1.f / 32.f);
      float dv = v - mu;
      float s2 = dv * dv;
      for (int m = 16; m >= 1; m >>= 1) s2 += __shfl_xor(s2, m);
      float xn = dv * rsqrtf(s2 * (1.f / 32.f) + 1e-5f) * gg + bb;
      float sc = xn * aw;
      for (int m = 16; m >= 1; m >>= 1) sc += __shfl_xor(sc, m);
      if (act) {
        xr[(size_t)bn * CC + j * FF + f] = __float2bfloat16(xn);
        if (f == 0) scores[bn * JJ + j] = sc + ab;
      }
    }
  } else {
    // ---- wconv body (weights -> bf16 padded; zero Qp/Kp kblk-8 pad halves)
    int wb = bid - BN / 4;
    if (wb < NCQP + NCPP) {
      bool isq = wb < NCQP;
      int r = isq ? wb : wb - NCQP;
      const float* src = isq ? qkv_w : proj_w;
      __hip_bfloat16* dst = isq ? qw : pw;
      int nrows = isq ? NCQ : CC;
      if (t < KD / 4) {
        int c = t * 4;
        float4 v;
        if (r < nrows) v = *(const float4*)(src + (size_t)r * KD + c);
        else           v = float4{0.f, 0.f, 0.f, 0.f};
        __hip_bfloat16 o[4] = {__float2bfloat16(v.x), __float2bfloat16(v.y),
                               __float2bfloat16(v.z), __float2bfloat16(v.w)};
        *(unsigned long long*)(dst + (size_t)r * KD + c) = *(unsigned long long*)o;
      }
    } else {
      int row = (wb - (NCQP + NCPP)) * 256 + t;  // 131072 = 128 bh-tensors x 1024 n
      if (row < 131072) {
        int bhT = row >> 10, n = row & 1023;
        // byte offset: bhT slabs of 147456B; kblk 8 at +131072B; n*16B; high 8B
        char* p = qkp + (size_t)bhT * 147456 + 131072 + (size_t)n * 16 + 8;
        *(unsigned long long*)p = 0ull;
      }
    }
  }
}

// ---------------------------------------------------------------- K2: per-(b,j) softmax stats over N -> {max, 1/sum}
__global__ __launch_bounds__(256) void softmax_red(const float* __restrict__ scores,
                                                   float2* __restrict__ tab) {
  int bj = blockIdx.x;
  int b = bj / JJ, j = bj - b * JJ;
  const float* s = scores + (size_t)b * NN * JJ + j;
  int t = threadIdx.x;
  float v[4];
  float mx = -1e30f;
#pragma unroll
  for (int i = 0; i < 4; ++i) { v[i] = s[(t + 256 * i) * JJ]; mx = fmaxf(mx, v[i]); }
#pragma unroll
  for (int m = 32; m >= 1; m >>= 1) mx = fmaxf(mx, __shfl_xor(mx, m));
  __shared__ float red[4];
  if ((t & 63) == 0) red[t >> 6] = mx;
  __syncthreads();
  mx = fmaxf(fmaxf(red[0], red[1]), fmaxf(red[2], red[3]));
  float sum = 0.f;
#pragma unroll
  for (int i = 0; i < 4; ++i) sum += __expf(v[i] - mx);
#pragma unroll
  for (int m = 32; m >= 1; m >>= 1) sum += __shfl_xor(sum, m);
  __shared__ float red2[4];
  if ((t & 63) == 0) red2[t >> 6] = sum;
  __syncthreads();
  if (t == 0) {
    sum = red2[0] + red2[1] + red2[2] + red2[3];
    tab[bj] = make_float2(mx, 1.f / sum);
  }
}

// ---------------------------------------------------------------- K3: xp = xr*w (w recomputed from scores+tab), LN2, -> bf16
__global__ __launch_bounds__(256) void ln2_xp(const __hip_bfloat16* __restrict__ xr,
                                              const float* __restrict__ scores,
                                              const float2* __restrict__ tab,
                                              const float* __restrict__ g2,
                                              const float* __restrict__ b2,
                                              __hip_bfloat16* __restrict__ xp) {
  __shared__ float wsh[4][JJ];
  int wv = threadIdx.x >> 6, lane = threadIdx.x & 63;
  int bn = blockIdx.x * 4 + wv;
  if (lane < JJ) {
    float sc = scores[bn * JJ + lane];
    float2 mi = tab[(bn >> 10) * JJ + lane];
    wsh[wv][lane] = __expf(sc - mi.x) * mi.y;
  }
  // same-wave producer/consumer: lgkmcnt ordering suffices, no __syncthreads
  float vals[9];
  float sum = 0.f;
  for (int it = 0; it < 9; ++it) {
    int c = it * 64 + lane;
    float v = 0.f;
    if (c < CC) v = __bfloat162float(xr[(size_t)bn * CC + c]) * wsh[wv][c >> 5];
    vals[it] = v;
    sum += v;
  }
  for (int m = 32; m >= 1; m >>= 1) sum += __shfl_xor(sum, m);
  float mu = sum * (1.f / 544.f);
  float s2 = 0.f;
  for (int it = 0; it < 9; ++it) {
    int c = it * 64 + lane;
    if (c < CC) { float dv = vals[it] - mu; s2 += dv * dv; }
  }
  for (int m = 32; m >= 1; m >>= 1) s2 += __shfl_xor(s2, m);
  float rstd = rsqrtf(s2 * (1.f / 544.f) + 1e-5f);
  for (int it = 0; it < 9; ++it) {
    int c = it * 64 + lane;
    if (c < CC)
      xp[(size_t)bn * CC + c] = __float2bfloat16((vals[it] - mu) * rstd * g2[c] + b2[c]);
  }
}

// ---------------------------------------------------------------- GEMM: C[M,N] = A[M,K] * B[N,K]^T, bf16 MFMA
// R19 (kept): MODE 0 epilogue routes Q/K/V through the freed As/Bs LDS and
// emits layout-exact WIDE stores (Q/K 8B packets, V 16B segments).
// R22: L2-aware grid remap. Old map (by = (bi>>3)>>3) scattered the NBY
// blocks sharing one 139KB A-panel across the whole dispatch -> A re-fetched
// NBY times (~116MB via L3). New map makes by the FASTEST axis within each
// XCD (bx = xcd*8 + q/NBY, by = q%NBY): the NBY A-panel consumers are
// consecutive on one XCD -> panel lives in that XCD's L2 (35 TB/s), fetched
// once. B stays L2/L3-resident as before. Bijective: 832=8*8*13, 320=8*8*5.
template <int MODE>
__global__ __launch_bounds__(256) void gemm_nt(const __hip_bfloat16* __restrict__ A,
                                               const __hip_bfloat16* __restrict__ Bw,
                                               __hip_bfloat16* __restrict__ Qp,
                                               __hip_bfloat16* __restrict__ Kp,
                                               __hip_bfloat16* __restrict__ Vt,
                                               float* __restrict__ Cf,
                                               const float* __restrict__ bias,
                                               const float* __restrict__ sfp) {
  extern __shared__ char smem[];  // 34816B: K-loop = As[2]|Bs[2] (32KB); MODE0 epilogue = Cst[128][136] bf16
  __hip_bfloat16 (*As)[128 * 32] = (__hip_bfloat16 (*)[128 * 32])(smem);
  __hip_bfloat16 (*Bs)[128 * 32] = (__hip_bfloat16 (*)[128 * 32])(smem + 16384);
  const int t = threadIdx.x;
  const int w = t >> 6, lane = t & 63;
  const int fr = lane & 15, fq = lane >> 4;
  const int bi = blockIdx.x;
  constexpr int NBY = (MODE == 0) ? 13 : 5;
  const int xcd = bi & 7, q = bi >> 3;
  const int bxl = q / NBY, by = q - bxl * NBY;
  const int bx = xcd * 8 + bxl;
  const int m0 = bx * 128;
  const int n0 = by * 128;
  const int wm = (w >> 1) * 64, wn = (w & 1) * 64;

  f32x4 acc[4][4] = {};

  const __hip_bfloat16* Ag = A + (size_t)m0 * KD;
  const __hip_bfloat16* Bg = Bw + (size_t)n0 * KD;

#pragma unroll
  for (int i2 = 0; i2 < 2; ++i2) {
    int cb = (i2 * 4 + w) * 64;
    int chunk = cb + lane;
    int row = chunk >> 2, c16 = chunk & 3;
    gld_lds16(Ag + (size_t)row * KD + c16 * 8, &As[0][cb * 8]);
    gld_lds16(Bg + (size_t)row * KD + c16 * 8, &Bs[0][cb * 8]);
  }
  __syncthreads();

  for (int kt = 0; kt < 17; ++kt) {
    const int cur = kt & 1;
    if (kt < 16) {
      const int k0 = (kt + 1) * 32;
#pragma unroll
      for (int i2 = 0; i2 < 2; ++i2) {
        int cb = (i2 * 4 + w) * 64;
        int chunk = cb + lane;
        int row = chunk >> 2, c16 = chunk & 3;
        gld_lds16(Ag + (size_t)row * KD + k0 + c16 * 8, &As[1 - cur][cb * 8]);
        gld_lds16(Bg + (size_t)row * KD + k0 + c16 * 8, &Bs[1 - cur][cb * 8]);
      }
    }
    bf16x8 af[4], bfr[4];
#pragma unroll
    for (int tm = 0; tm < 4; ++tm)
      af[tm] = *(const bf16x8*)&As[cur][(wm + tm * 16 + fr) * 32 + fq * 8];
#pragma unroll
    for (int tn = 0; tn < 4; ++tn)
      bfr[tn] = *(const bf16x8*)&Bs[cur][(wn + tn * 16 + fr) * 32 + fq * 8];
#pragma unroll
    for (int tm = 0; tm < 4; ++tm)
#pragma unroll
      for (int tn = 0; tn < 4; ++tn)
        acc[tm][tn] = __builtin_amdgcn_mfma_f32_16x16x32_bf16(af[tm], bfr[tn], acc[tm][tn], 0, 0, 0);
    __syncthreads();  // cur reads done; drains kt+1 prefetch (hidden behind MFMAs)
  }

  if (MODE == 1) {
#pragma unroll
    for (int tn = 0; tn < 4; ++tn) {
      int o = n0 + wn + tn * 16 + fr;
      if (o < CC) {
        float bb = bias[o];
#pragma unroll
        for (int tm = 0; tm < 4; ++tm) {
          int m = m0 + wm + tm * 16 + fq * 4;
#pragma unroll
          for (int r = 0; r < 4; ++r)
            Cf[(size_t)(m + r) * CC + o] = acc[tm][tn][r] + bb;
        }
      }
    }
  } else {
    const int b = m0 >> 10;
    const int nbase = m0 & (NN - 1);
    const float sf = sfp[0];
    __hip_bfloat16* Cst = (__hip_bfloat16*)smem;  // [128 o][136 m]; rows 272B (16B-aligned)

    // ---- stage the 128x128 tile into LDS (K pos-scale folded here)
#pragma unroll
    for (int tn = 0; tn < 4; ++tn) {
      int olocal = wn + tn * 16 + fr;
      int o = n0 + olocal;
      bool isk = (o >= CC) && (o < 2 * CC);
#pragma unroll
      for (int tm = 0; tm < 4; ++tm) {
        int mloc = wm + tm * 16 + fq * 4;
        int n = nbase + mloc;
#pragma unroll
        for (int r = 0; r < 4; ++r) {
          float v = acc[tm][tn][r];
          if (isk) {
            float pos = (n + r) * (1.f / 1023.f) - 0.5f;
            v *= __expf(-sf * pos * pos) * (0.12126781251816650f * 1.44269504088896340f);
          }
          Cst[olocal * 136 + mloc + r] = __float2bfloat16(v);
        }
      }
    }
    __syncthreads();

    // ---- Q/K: 8B stores; 4-dim groups (q/k and head boundaries are 4-aligned)
    for (int s = t; s < 32 * 128; s += 256) {
      int g = s >> 7, nl = s & 127;
      int o = n0 + g * 4;
      if (o < 2 * CC) {
        bool isk = o >= CC;
        int oo = isk ? o - CC : o;
        int h = oo / HD;
        int d0 = oo - h * HD;  // 4-aligned; d0&7 in {0,4}; d0>>3 uniform over the group
        unsigned long long pk;
        __hip_bfloat16* pp = (__hip_bfloat16*)&pk;
#pragma unroll
        for (int j2 = 0; j2 < 4; ++j2) pp[j2] = Cst[(g * 4 + j2) * 136 + nl];
        __hip_bfloat16* basep = isk ? Kp : Qp;
        size_t ei = (size_t)(b * HH + h) * BHSZ + (size_t)(d0 >> 3) * (NN * 8) +
                    (size_t)(nbase + nl) * 8 + (d0 & 7);
        *(unsigned long long*)(basep + ei) = pk;
      }
    }
    // ---- V: 16B row-segment stores (Vt is d-major; each Cst o-row is one d-row)
    {
      int lo = 2 * CC - n0; if (lo < 0) lo = 0;   // first V o_local
      int hi = NCQ - n0;    if (hi > 128) hi = 128;  // end o_local (pad excluded)
      if (hi > lo) {
        int nv = hi - lo;
        for (int s = t; s < nv * 16; s += 256) {
          int row = lo + (s >> 4), seg = s & 15;
          int oo = n0 + row - 2 * CC;
          int h = oo / HD;
          int d = oo - h * HD;
          bf16x8 v8 = *(const bf16x8*)&Cst[row * 136 + seg * 8];
          __hip_bfloat16* vdst = Vt + ((size_t)(b * HH + h) * HD + d) * NN + nbase + seg * 8;
          *(bf16x8*)vdst = v8;
        }
      }
    }
  }
}

// ---------------------------------------------------------------- Flash attention (R14 exact — FROZEN, setprio removed)
// Ten structural variants (R9/R12/R13/R15b/R16/R17/R18/R20b) measured
// 55-98us vs this shape's 54us. R21's setprio add-on regressed it to 56.1
// (m190 regime: barrier-locked waves have no role diversity to arbitrate)
// and is removed. This is the final attn shape.
__global__ __launch_bounds__(128) void attn_kernel(const __hip_bfloat16* __restrict__ Qp,
                                                   const __hip_bfloat16* __restrict__ Kp,
                                                   const __hip_bfloat16* __restrict__ Vt,
                                                   __hip_bfloat16* __restrict__ Ao) {
  __shared__ __hip_bfloat16 Qs[NKB * 64 * 8];     // 9216B: Q staging; Ps[4][16][72] scratch in loop
  __shared__ __hip_bfloat16 Ks[2][NKB * 64 * 8];  // 2 x 9216B double buffer
  __shared__ __hip_bfloat16 Zs[64 * 8];           // 1024B zeros (virtual kblks 9..11)
  const int t = threadIdx.x;
  const int w = t >> 6, lane = t & 63;
  const int fr = lane & 15, fq = lane >> 4;
  const int idx = blockIdx.x;
  const int bh = idx & 63, qt = idx >> 6;
  const int h = bh & 7, b = bh >> 3;

  const __hip_bfloat16* qtile = Qp + (size_t)bh * BHSZ + (size_t)qt * AQR * 8;
  const __hip_bfloat16* kbase = Kp + (size_t)bh * BHSZ;
  const __hip_bfloat16* vbase = Vt + (size_t)bh * HD * NN;

  // ---- prologue: zero block; Q + K0 via DMA. k-major: inst kb loads 64 rows x 16B contiguous.
  *(unsigned long long*)&Zs[t * 4] = 0ull;
#pragma unroll
  for (int i = 0; i < 5; ++i) {
    int kb = i * 2 + w;  // wave-uniform kblk; wave0: 0,2,4,6,8  wave1: 1,3,5,7
    if (kb < NKB) gld_lds16(qtile + (size_t)kb * (NN * 8) + lane * 8, &Qs[kb * 64 * 8]);
  }
#pragma unroll
  for (int i = 0; i < 5; ++i) {
    int kb = i * 2 + w;
    if (kb < NKB) gld_lds16(kbase + (size_t)kb * (NN * 8) + lane * 8, &Ks[0][kb * 64 * 8]);
  }
  __syncthreads();  // drain Q + K0 DMA + Zs writes
  bf16x8 qa[2][3];
#pragma unroll
  for (int ks = 0; ks < 3; ++ks) {
    const __hip_bfloat16* qb = (ks < 2 || fq == 0) ? &Qs[(ks * 4 + fq) * 512] : Zs;
#pragma unroll
    for (int g = 0; g < 2; ++g)
      qa[g][ks] = *(const bf16x8*)&qb[(w * 32 + g * 16 + fr) * 8];
  }
  __syncthreads();  // all waves done reading Qs before it becomes Ps scratch

  f32x4 o_acc[2][5] = {};
  float l_part[2][4] = {};
  const int dclamp = (fr < 4) ? 0 : 1;  // tv=4 rows 64+fr valid only for fr<4

  for (int kt = 0; kt < 16; ++kt) {
    const int cur = kt & 1;
    // ---- V(kt) -> registers (issued first so the vfrag waitcnt leaves K DMA in flight)
    bf16x8 vfrag[5][2];
#pragma unroll
    for (int tv = 0; tv < 5; ++tv) {
      int d = tv * 16 + fr;
      int dc = (tv == 4 && dclamp) ? 0 : d;  // clamp OOB rows; outputs discarded
#pragma unroll
      for (int ks2 = 0; ks2 < 2; ++ks2)
        vfrag[tv][ks2] = *(const bf16x8*)(vbase + (size_t)dc * NN + kt * 64 + ks2 * 32 + fq * 8);
    }
    // ---- K(kt+1) DMA into the other buffer; drained at the END-of-tile barrier
    if (kt < 15) {
      const __hip_bfloat16* ktile = kbase + (size_t)(kt + 1) * 64 * 8;
#pragma unroll
      for (int i = 0; i < 5; ++i) {
        int kb = i * 2 + w;
        if (kb < NKB) gld_lds16(ktile + (size_t)kb * (NN * 8) + lane * 8, &Ks[1 - cur][kb * 64 * 8]);
      }
    }

    // ---- S = Q K^T for both row-groups; each K fragment load feeds 2 MFMAs
    f32x4 s[2][4] = {};
#pragma unroll
    for (int ks = 0; ks < 3; ++ks) {
      const __hip_bfloat16* kbL = (ks < 2 || fq == 0) ? &Ks[cur][(ks * 4 + fq) * 512] : Zs;
#pragma unroll
      for (int tn = 0; tn < 4; ++tn) {
        bf16x8 kb = *(const bf16x8*)&kbL[(tn * 16 + fr) * 8];
        s[0][tn] = __builtin_amdgcn_mfma_f32_16x16x32_bf16(qa[0][ks], kb, s[0][tn], 0, 0, 0);
        s[1][tn] = __builtin_amdgcn_mfma_f32_16x16x32_bf16(qa[1][ks], kb, s[1][tn], 0, 0, 0);
      }
    }
    // ---- no-max softmax: p = exp2(s) (log2e pre-folded into K); per-lane partial row sums
#pragma unroll
    for (int g = 0; g < 2; ++g) {
      __hip_bfloat16* Pw = &Qs[(w * 2 + g) * 1152];  // 16x72 per-wave-group region
#pragma unroll
      for (int tn = 0; tn < 4; ++tn)
#pragma unroll
        for (int r = 0; r < 4; ++r) {
          float pe = __builtin_amdgcn_exp2f(s[g][tn][r]);
          l_part[g][r] += pe;
          Pw[(fq * 4 + r) * 72 + tn * 16 + fr] = __float2bfloat16(pe);
        }
    }
    // ---- O += P V; V fragments from registers
#pragma unroll
    for (int ks2 = 0; ks2 < 2; ++ks2) {
      bf16x8 pa0 = *(const bf16x8*)&Qs[(w * 2 + 0) * 1152 + fr * 72 + ks2 * 32 + fq * 8];
      bf16x8 pa1 = *(const bf16x8*)&Qs[(w * 2 + 1) * 1152 + fr * 72 + ks2 * 32 + fq * 8];
#pragma unroll
      for (int tv = 0; tv < 5; ++tv) {
        o_acc[0][tv] = __builtin_amdgcn_mfma_f32_16x16x32_bf16(pa0, vfrag[tv][ks2], o_acc[0][tv], 0, 0, 0);
        o_acc[1][tv] = __builtin_amdgcn_mfma_f32_16x16x32_bf16(pa1, vfrag[tv][ks2], o_acc[1][tv], 0, 0, 0);
      }
    }
    __syncthreads();  // end of tile: Ks[cur]/Ps reads done; drains kt+1 prefetch (hidden)
  }
  // ---- epilogue: reduce l across the 16 row-lanes (4 shfls, once), O / l -> bf16
#pragma unroll
  for (int g = 0; g < 2; ++g) {
    __hip_bfloat16* obase = Ao + (size_t)(b * NN + qt * AQR + w * 32 + g * 16) * CC + h * HD;
    float inv[4];
#pragma unroll
    for (int r = 0; r < 4; ++r) {
      float l = l_part[g][r];
#pragma unroll
      for (int msk = 8; msk >= 1; msk >>= 1) l += __shfl_xor(l, msk);
      inv[r] = 1.f / l;
    }
#pragma unroll
    for (int tv = 0; tv < 5; ++tv) {
      int d = tv * 16 + fr;
      if (d < HD) {
#pragma unroll
        for (int r = 0; r < 4; ++r)
          obase[(size_t)(fq * 4 + r) * CC + d] = __float2bfloat16(o_acc[g][tv][r] * inv[r]);
      }
    }
  }
}

// ---------------------------------------------------------------- launch
extern "C" void kernel_launch(void* const* d_in, const int* in_sizes, int n_in,
                              void* d_out, int out_size, void* d_ws, size_t ws_size,
                              hipStream_t stream) {
  (void)in_sizes; (void)n_in; (void)out_size; (void)ws_size;
  const float* x       = (const float*)d_in[0];
  const float* norm_g  = (const float*)d_in[1];
  const float* norm_b  = (const float*)d_in[2];
  const float* ap_w    = (const float*)d_in[3];
  const float* ap_b    = (const float*)d_in[4];
  const float* norm2_g = (const float*)d_in[5];
  const float* norm2_b = (const float*)d_in[6];
  const float* qkv_w   = (const float*)d_in[7];
  const float* proj_w  = (const float*)d_in[8];
  const float* proj_b  = (const float*)d_in[9];
  const float* sf      = (const float*)d_in[10];
  float* out = (float*)d_out;
  char* ws = (char*)d_ws;

  // workspace layout (bytes) — 57.6MB total (qp/kp: 9 kblk k-major slabs)
  __hip_bfloat16* xr   = (__hip_bfloat16*)(ws);                // 8192*544*2  = 8912896
  float* scores        = (float*)(ws + 8912896);               // 8192*17*4   = 557056
  float2* tab          = (float2*)(ws + 9469952);              // 136*8 -> pad 4096
  __hip_bfloat16* xp   = (__hip_bfloat16*)(ws + 9474048);      // 8912896
  __hip_bfloat16* qw   = (__hip_bfloat16*)(ws + 18386944);     // 1664*544*2  = 1810432
  __hip_bfloat16* pw   = (__hip_bfloat16*)(ws + 20197376);     // 640*544*2   = 696320
  __hip_bfloat16* vt   = (__hip_bfloat16*)(ws + 20893696);     // 8*8*68*1024*2 = 8912896
  __hip_bfloat16* ao   = (__hip_bfloat16*)(ws + 29806592);     // 8912896
  __hip_bfloat16* qp   = (__hip_bfloat16*)(ws + 38719488);     // 64*73728*2 = 9437184
  __hip_bfloat16* kp   = (__hip_bfloat16*)(ws + 48156672);     // 9437184 (contiguous after qp for wconv pad-zeroing)
  // total 57593856 bytes

  wconv_ln1<<<BN / 4 + NCQP + NCPP + 512, 256, 0, stream>>>(
      x, norm_g, norm_b, ap_w, ap_b, xr, scores, qkv_w, proj_w, qw, pw, (char*)qp);
  softmax_red<<<BB * JJ, 256, 0, stream>>>(scores, tab);
  ln2_xp<<<BN / 4, 256, 0, stream>>>(xr, scores, tab, norm2_g, norm2_b, xp);
  gemm_nt<0><<<dim3(64 * 13), 256, 34816, stream>>>(xp, qw, qp, kp, vt, nullptr, nullptr, sf);
  attn_kernel<<<dim3((NN / AQR) * HH * BB), 128, 0, stream>>>(qp, kp, vt, ao);
  gemm_nt<1><<<dim3(64 * 5), 256, 34816, stream>>>(ao, pw, nullptr, nullptr, nullptr, out, proj_b, nullptr);
}

// Round 15
// 198.530 us; speedup vs baseline: 1.1228x; 1.0046x over previous
//
#include <hip/hip_runtime.h>
#include <hip/hip_bf16.h>

// Problem constants
#define BB 8
#define NN 1024
#define CC 544      // J*F = 17*32
#define JJ 17
#define FF 32
#define HH 8
#define HD 68
#define BN 8192     // B*N
#define KD 544      // GEMM K dim (=C)
#define NCQ 1632    // 3*C
#define NCQP 1664   // padded to 13*128
#define NCPP 640    // proj out padded to 5*128
#define NKB 9       // k-blocks (8 dims each) stored for Q/K: 72 dims; 68 valid
#define BHSZ 73728  // elements per (b,h) Q/K slab: NKB*1024*8
#define AQR 64      // q-rows per attention block (2 waves x 2 groups x 16)

using f32x4  = __attribute__((ext_vector_type(4))) float;
using bf16x8 = __attribute__((ext_vector_type(8))) short;

__device__ __forceinline__ void gld_lds16(const void* g, void* l) {
  __builtin_amdgcn_global_load_lds(
      (const __attribute__((address_space(1))) void*)g,
      (__attribute__((address_space(3))) void*)l, 16, 0, 0);
}

__device__ __forceinline__ float bf16bits2f(short bits) {
  // bf16 -> f32 is exact: place bits in the high half
  return __uint_as_float(((unsigned)(unsigned short)bits) << 16);
}

// ---------------------------------------------------------------- K0+K1 merged: weight conversion + LN1/scores
// R23: pad-zero segment removed (folded into gemm_nt<0> epilogue).
__global__ __launch_bounds__(256) void wconv_ln1(const float* __restrict__ x,
                                                 const float* __restrict__ g,
                                                 const float* __restrict__ bta,
                                                 const float* __restrict__ apw,
                                                 const float* __restrict__ apb,
                                                 __hip_bfloat16* __restrict__ xr,
                                                 float* __restrict__ scores,
                                                 const float* __restrict__ qkv_w,
                                                 const float* __restrict__ proj_w,
                                                 __hip_bfloat16* __restrict__ qw,
                                                 __hip_bfloat16* __restrict__ pw) {
  int bid = blockIdx.x, t = threadIdx.x;
  if (bid < BN / 4) {
    // ---- ln1_scores body (4 waves = 4 tokens per block)
    int wv = t >> 6, lane = t & 63;
    int bn = bid * 4 + wv;
    int f = lane & 31, half = lane >> 5;
    const float* row = x + (size_t)bn * CC;
    float gg = g[f], bb = bta[f], aw = apw[f], ab = apb[0];
    for (int it = 0; it < 9; ++it) {
      int j = it * 2 + half;
      bool act = (j < JJ);
      float v = act ? row[j * FF + f] : 0.f;
      float s = v;
      for (int m = 16; m >= 1; m >>= 1) s += __shfl_xor(s, m);
      float mu = s * (1.f / 32.f);
      float dv = v - mu;
      float s2 = dv * dv;
      for (int m = 16; m >= 1; m >>= 1) s2 += __shfl_xor(s2, m);
      float xn = dv * rsqrtf(s2 * (1.f / 32.f) + 1e-5f) * gg + bb;
      float sc = xn * aw;
      for (int m = 16; m >= 1; m >>= 1) sc += __shfl_xor(sc, m);
      if (act) {
        xr[(size_t)bn * CC + j * FF + f] = __float2bfloat16(xn);
        if (f == 0) scores[bn * JJ + j] = sc + ab;
      }
    }
  } else {
    // ---- wconv body (weights -> bf16 padded)
    int wb = bid - BN / 4;
    bool isq = wb < NCQP;
    int r = isq ? wb : wb - NCQP;
    const float* src = isq ? qkv_w : proj_w;
    __hip_bfloat16* dst = isq ? qw : pw;
    int nrows = isq ? NCQ : CC;
    if (t < KD / 4) {
      int c = t * 4;
      float4 v;
      if (r < nrows) v = *(const float4*)(src + (size_t)r * KD + c);
      else           v = float4{0.f, 0.f, 0.f, 0.f};
      __hip_bfloat16 o[4] = {__float2bfloat16(v.x), __float2bfloat16(v.y),
                             __float2bfloat16(v.z), __float2bfloat16(v.w)};
      *(unsigned long long*)(dst + (size_t)r * KD + c) = *(unsigned long long*)o;
    }
  }
}

// ---------------------------------------------------------------- K2: per-(b,j) softmax stats over N -> {max, 1/sum}
__global__ __launch_bounds__(256) void softmax_red(const float* __restrict__ scores,
                                                   float2* __restrict__ tab) {
  int bj = blockIdx.x;
  int b = bj / JJ, j = bj - b * JJ;
  const float* s = scores + (size_t)b * NN * JJ + j;
  int t = threadIdx.x;
  float v[4];
  float mx = -1e30f;
#pragma unroll
  for (int i = 0; i < 4; ++i) { v[i] = s[(t + 256 * i) * JJ]; mx = fmaxf(mx, v[i]); }
#pragma unroll
  for (int m = 32; m >= 1; m >>= 1) mx = fmaxf(mx, __shfl_xor(mx, m));
  __shared__ float red[4];
  if ((t & 63) == 0) red[t >> 6] = mx;
  __syncthreads();
  mx = fmaxf(fmaxf(red[0], red[1]), fmaxf(red[2], red[3]));
  float sum = 0.f;
#pragma unroll
  for (int i = 0; i < 4; ++i) sum += __expf(v[i] - mx);
#pragma unroll
  for (int m = 32; m >= 1; m >>= 1) sum += __shfl_xor(sum, m);
  __shared__ float red2[4];
  if ((t & 63) == 0) red2[t >> 6] = sum;
  __syncthreads();
  if (t == 0) {
    sum = red2[0] + red2[1] + red2[2] + red2[3];
    tab[bj] = make_float2(mx, 1.f / sum);
  }
}

// ---------------------------------------------------------------- K3: xp = xr*w, LN2, -> bf16 (R23b: bf16x8 vectorized, G13)
// Was scalar 2B/lane loads+stores (Common-mistake #2, ~2x cost). Now each
// lane handles one 16B chunk (8 elems); lanes 0..3 take the tail chunks
// 64..67 (elems 512..543 = joint 16). Vector elements converted via bit
// arithmetic (bits<<16), not address-of (clang rejects &vec[i]).
__global__ __launch_bounds__(256) void ln2_xp(const __hip_bfloat16* __restrict__ xr,
                                              const float* __restrict__ scores,
                                              const float2* __restrict__ tab,
                                              const float* __restrict__ g2,
                                              const float* __restrict__ b2,
                                              __hip_bfloat16* __restrict__ xp) {
  __shared__ float wsh[4][JJ];
  int wv = threadIdx.x >> 6, lane = threadIdx.x & 63;
  int bn = blockIdx.x * 4 + wv;
  if (lane < JJ) {
    float sc = scores[bn * JJ + lane];
    float2 mi = tab[(bn >> 10) * JJ + lane];
    wsh[wv][lane] = __expf(sc - mi.x) * mi.y;
  }
  const __hip_bfloat16* row = xr + (size_t)bn * CC;
  const bool has2 = (lane < 4);
  bf16x8 c0 = *(const bf16x8*)(row + lane * 8);
  bf16x8 c1 = {};
  if (has2) c1 = *(const bf16x8*)(row + (64 + lane) * 8);
  // same-wave LDS RAW on wsh: lgkmcnt ordering suffices (writers are lanes 0..16 of this wave)
  float w0 = wsh[wv][lane >> 2];
  float w1 = wsh[wv][16];
  float v0[8], v1[8];
  float sum = 0.f;
#pragma unroll
  for (int i = 0; i < 8; ++i) {
    v0[i] = bf16bits2f(c0[i]) * w0;
    sum += v0[i];
  }
#pragma unroll
  for (int i = 0; i < 8; ++i) {
    v1[i] = has2 ? bf16bits2f(c1[i]) * w1 : 0.f;
    sum += v1[i];
  }
  for (int m = 32; m >= 1; m >>= 1) sum += __shfl_xor(sum, m);
  float mu = sum * (1.f / 544.f);
  float s2 = 0.f;
#pragma unroll
  for (int i = 0; i < 8; ++i) { float dv = v0[i] - mu; s2 += dv * dv; }
  if (has2) {
#pragma unroll
    for (int i = 0; i < 8; ++i) { float dv = v1[i] - mu; s2 += dv * dv; }
  }
  for (int m = 32; m >= 1; m >>= 1) s2 += __shfl_xor(s2, m);
  float rstd = rsqrtf(s2 * (1.f / 544.f) + 1e-5f);
  __hip_bfloat16* dst = xp + (size_t)bn * CC;
  {
    float4 ga = *(const float4*)(g2 + lane * 8);
    float4 gb = *(const float4*)(g2 + lane * 8 + 4);
    float4 ba = *(const float4*)(b2 + lane * 8);
    float4 bb4 = *(const float4*)(b2 + lane * 8 + 4);
    float gg[8] = {ga.x, ga.y, ga.z, ga.w, gb.x, gb.y, gb.z, gb.w};
    float bbv[8] = {ba.x, ba.y, ba.z, ba.w, bb4.x, bb4.y, bb4.z, bb4.w};
    bf16x8 o;
#pragma unroll
    for (int i = 0; i < 8; ++i) {
      __hip_bfloat16 h = __float2bfloat16((v0[i] - mu) * rstd * gg[i] + bbv[i]);
      o[i] = *(short*)&h;
    }
    *(bf16x8*)(dst + lane * 8) = o;
  }
  if (has2) {
    float4 ga = *(const float4*)(g2 + 512 + lane * 8);
    float4 gb = *(const float4*)(g2 + 512 + lane * 8 + 4);
    float4 ba = *(const float4*)(b2 + 512 + lane * 8);
    float4 bb4 = *(const float4*)(b2 + 512 + lane * 8 + 4);
    float gg[8] = {ga.x, ga.y, ga.z, ga.w, gb.x, gb.y, gb.z, gb.w};
    float bbv[8] = {ba.x, ba.y, ba.z, ba.w, bb4.x, bb4.y, bb4.z, bb4.w};
    bf16x8 o;
#pragma unroll
    for (int i = 0; i < 8; ++i) {
      __hip_bfloat16 h = __float2bfloat16((v1[i] - mu) * rstd * gg[i] + bbv[i]);
      o[i] = *(short*)&h;
    }
    *(bf16x8*)(dst + 512 + lane * 8) = o;
  }
}

// ---------------------------------------------------------------- GEMM: C[M,N] = A[M,K] * B[N,K]^T, bf16 MFMA
// R19: MODE 0 epilogue wide stores (Q/K 8B packets, V 16B segments).
// R22: L2-aware grid remap (kept, neutral). R23: kblk-8 pad zeros emitted
// here (d0==64 group writes 8B zero at +4), replacing wconv's pad pass.
template <int MODE>
__global__ __launch_bounds__(256) void gemm_nt(const __hip_bfloat16* __restrict__ A,
                                               const __hip_bfloat16* __restrict__ Bw,
                                               __hip_bfloat16* __restrict__ Qp,
                                               __hip_bfloat16* __restrict__ Kp,
                                               __hip_bfloat16* __restrict__ Vt,
                                               float* __restrict__ Cf,
                                               const float* __restrict__ bias,
                                               const float* __restrict__ sfp) {
  extern __shared__ char smem[];  // 34816B: K-loop = As[2]|Bs[2] (32KB); MODE0 epilogue = Cst[128][136] bf16
  __hip_bfloat16 (*As)[128 * 32] = (__hip_bfloat16 (*)[128 * 32])(smem);
  __hip_bfloat16 (*Bs)[128 * 32] = (__hip_bfloat16 (*)[128 * 32])(smem + 16384);
  const int t = threadIdx.x;
  const int w = t >> 6, lane = t & 63;
  const int fr = lane & 15, fq = lane >> 4;
  const int bi = blockIdx.x;
  constexpr int NBY = (MODE == 0) ? 13 : 5;
  const int xcd = bi & 7, q = bi >> 3;
  const int bxl = q / NBY, by = q - bxl * NBY;
  const int bx = xcd * 8 + bxl;
  const int m0 = bx * 128;
  const int n0 = by * 128;
  const int wm = (w >> 1) * 64, wn = (w & 1) * 64;

  f32x4 acc[4][4] = {};

  const __hip_bfloat16* Ag = A + (size_t)m0 * KD;
  const __hip_bfloat16* Bg = Bw + (size_t)n0 * KD;

#pragma unroll
  for (int i2 = 0; i2 < 2; ++i2) {
    int cb = (i2 * 4 + w) * 64;
    int chunk = cb + lane;
    int row = chunk >> 2, c16 = chunk & 3;
    gld_lds16(Ag + (size_t)row * KD + c16 * 8, &As[0][cb * 8]);
    gld_lds16(Bg + (size_t)row * KD + c16 * 8, &Bs[0][cb * 8]);
  }
  __syncthreads();

  for (int kt = 0; kt < 17; ++kt) {
    const int cur = kt & 1;
    if (kt < 16) {
      const int k0 = (kt + 1) * 32;
#pragma unroll
      for (int i2 = 0; i2 < 2; ++i2) {
        int cb = (i2 * 4 + w) * 64;
        int chunk = cb + lane;
        int row = chunk >> 2, c16 = chunk & 3;
        gld_lds16(Ag + (size_t)row * KD + k0 + c16 * 8, &As[1 - cur][cb * 8]);
        gld_lds16(Bg + (size_t)row * KD + k0 + c16 * 8, &Bs[1 - cur][cb * 8]);
      }
    }
    bf16x8 af[4], bfr[4];
#pragma unroll
    for (int tm = 0; tm < 4; ++tm)
      af[tm] = *(const bf16x8*)&As[cur][(wm + tm * 16 + fr) * 32 + fq * 8];
#pragma unroll
    for (int tn = 0; tn < 4; ++tn)
      bfr[tn] = *(const bf16x8*)&Bs[cur][(wn + tn * 16 + fr) * 32 + fq * 8];
#pragma unroll
    for (int tm = 0; tm < 4; ++tm)
#pragma unroll
      for (int tn = 0; tn < 4; ++tn)
        acc[tm][tn] = __builtin_amdgcn_mfma_f32_16x16x32_bf16(af[tm], bfr[tn], acc[tm][tn], 0, 0, 0);
    __syncthreads();  // cur reads done; drains kt+1 prefetch (hidden behind MFMAs)
  }

  if (MODE == 1) {
#pragma unroll
    for (int tn = 0; tn < 4; ++tn) {
      int o = n0 + wn + tn * 16 + fr;
      if (o < CC) {
        float bb = bias[o];
#pragma unroll
        for (int tm = 0; tm < 4; ++tm) {
          int m = m0 + wm + tm * 16 + fq * 4;
#pragma unroll
          for (int r = 0; r < 4; ++r)
            Cf[(size_t)(m + r) * CC + o] = acc[tm][tn][r] + bb;
        }
      }
    }
  } else {
    const int b = m0 >> 10;
    const int nbase = m0 & (NN - 1);
    const float sf = sfp[0];
    __hip_bfloat16* Cst = (__hip_bfloat16*)smem;  // [128 o][136 m]; rows 272B (16B-aligned)

    // ---- stage the 128x128 tile into LDS (K pos-scale folded here)
#pragma unroll
    for (int tn = 0; tn < 4; ++tn) {
      int olocal = wn + tn * 16 + fr;
      int o = n0 + olocal;
      bool isk = (o >= CC) && (o < 2 * CC);
#pragma unroll
      for (int tm = 0; tm < 4; ++tm) {
        int mloc = wm + tm * 16 + fq * 4;
        int n = nbase + mloc;
#pragma unroll
        for (int r = 0; r < 4; ++r) {
          float v = acc[tm][tn][r];
          if (isk) {
            float pos = (n + r) * (1.f / 1023.f) - 0.5f;
            v *= __expf(-sf * pos * pos) * (0.12126781251816650f * 1.44269504088896340f);
          }
          Cst[olocal * 136 + mloc + r] = __float2bfloat16(v);
        }
      }
    }
    __syncthreads();

    // ---- Q/K: 8B stores; 4-dim groups (q/k and head boundaries are 4-aligned).
    // d0==64 group also zeroes the kblk-8 pad (dims 68..71) -> replaces wconv's pad pass.
    for (int s = t; s < 32 * 128; s += 256) {
      int g = s >> 7, nl = s & 127;
      int o = n0 + g * 4;
      if (o < 2 * CC) {
        bool isk = o >= CC;
        int oo = isk ? o - CC : o;
        int h = oo / HD;
        int d0 = oo - h * HD;  // 4-aligned; d0&7 in {0,4}; d0>>3 uniform over the group
        unsigned long long pk;
        __hip_bfloat16* pp = (__hip_bfloat16*)&pk;
#pragma unroll
        for (int j2 = 0; j2 < 4; ++j2) pp[j2] = Cst[(g * 4 + j2) * 136 + nl];
        __hip_bfloat16* basep = isk ? Kp : Qp;
        size_t ei = (size_t)(b * HH + h) * BHSZ + (size_t)(d0 >> 3) * (NN * 8) +
                    (size_t)(nbase + nl) * 8 + (d0 & 7);
        *(unsigned long long*)(basep + ei) = pk;
        if (d0 == 64) *(unsigned long long*)(basep + ei + 4) = 0ull;
      }
    }
    // ---- V: 16B row-segment stores (Vt is d-major; each Cst o-row is one d-row)
    {
      int lo = 2 * CC - n0; if (lo < 0) lo = 0;   // first V o_local
      int hi = NCQ - n0;    if (hi > 128) hi = 128;  // end o_local (pad excluded)
      if (hi > lo) {
        int nv = hi - lo;
        for (int s = t; s < nv * 16; s += 256) {
          int row = lo + (s >> 4), seg = s & 15;
          int oo = n0 + row - 2 * CC;
          int h = oo / HD;
          int d = oo - h * HD;
          bf16x8 v8 = *(const bf16x8*)&Cst[row * 136 + seg * 8];
          __hip_bfloat16* vdst = Vt + ((size_t)(b * HH + h) * HD + d) * NN + nbase + seg * 8;
          *(bf16x8*)vdst = v8;
        }
      }
    }
  }
}

// ---------------------------------------------------------------- Flash attention (R14 exact — FROZEN)
// Ten structural variants (R9/R12/R13/R15b/R16/R17/R18/R20b) measured
// 55-98us vs this shape's 54-55us; R21's setprio regressed to 56 (removed).
__global__ __launch_bounds__(128) void attn_kernel(const __hip_bfloat16* __restrict__ Qp,
                                                   const __hip_bfloat16* __restrict__ Kp,
                                                   const __hip_bfloat16* __restrict__ Vt,
                                                   __hip_bfloat16* __restrict__ Ao) {
  __shared__ __hip_bfloat16 Qs[NKB * 64 * 8];     // 9216B: Q staging; Ps[4][16][72] scratch in loop
  __shared__ __hip_bfloat16 Ks[2][NKB * 64 * 8];  // 2 x 9216B double buffer
  __shared__ __hip_bfloat16 Zs[64 * 8];           // 1024B zeros (virtual kblks 9..11)
  const int t = threadIdx.x;
  const int w = t >> 6, lane = t & 63;
  const int fr = lane & 15, fq = lane >> 4;
  const int idx = blockIdx.x;
  const int bh = idx & 63, qt = idx >> 6;
  const int h = bh & 7, b = bh >> 3;

  const __hip_bfloat16* qtile = Qp + (size_t)bh * BHSZ + (size_t)qt * AQR * 8;
  const __hip_bfloat16* kbase = Kp + (size_t)bh * BHSZ;
  const __hip_bfloat16* vbase = Vt + (size_t)bh * HD * NN;

  // ---- prologue: zero block; Q + K0 via DMA. k-major: inst kb loads 64 rows x 16B contiguous.
  *(unsigned long long*)&Zs[t * 4] = 0ull;
#pragma unroll
  for (int i = 0; i < 5; ++i) {
    int kb = i * 2 + w;  // wave-uniform kblk; wave0: 0,2,4,6,8  wave1: 1,3,5,7
    if (kb < NKB) gld_lds16(qtile + (size_t)kb * (NN * 8) + lane * 8, &Qs[kb * 64 * 8]);
  }
#pragma unroll
  for (int i = 0; i < 5; ++i) {
    int kb = i * 2 + w;
    if (kb < NKB) gld_lds16(kbase + (size_t)kb * (NN * 8) + lane * 8, &Ks[0][kb * 64 * 8]);
  }
  __syncthreads();  // drain Q + K0 DMA + Zs writes
  bf16x8 qa[2][3];
#pragma unroll
  for (int ks = 0; ks < 3; ++ks) {
    const __hip_bfloat16* qb = (ks < 2 || fq == 0) ? &Qs[(ks * 4 + fq) * 512] : Zs;
#pragma unroll
    for (int g = 0; g < 2; ++g)
      qa[g][ks] = *(const bf16x8*)&qb[(w * 32 + g * 16 + fr) * 8];
  }
  __syncthreads();  // all waves done reading Qs before it becomes Ps scratch

  f32x4 o_acc[2][5] = {};
  float l_part[2][4] = {};
  const int dclamp = (fr < 4) ? 0 : 1;  // tv=4 rows 64+fr valid only for fr<4

  for (int kt = 0; kt < 16; ++kt) {
    const int cur = kt & 1;
    // ---- V(kt) -> registers (issued first so the vfrag waitcnt leaves K DMA in flight)
    bf16x8 vfrag[5][2];
#pragma unroll
    for (int tv = 0; tv < 5; ++tv) {
      int d = tv * 16 + fr;
      int dc = (tv == 4 && dclamp) ? 0 : d;  // clamp OOB rows; outputs discarded
#pragma unroll
      for (int ks2 = 0; ks2 < 2; ++ks2)
        vfrag[tv][ks2] = *(const bf16x8*)(vbase + (size_t)dc * NN + kt * 64 + ks2 * 32 + fq * 8);
    }
    // ---- K(kt+1) DMA into the other buffer; drained at the END-of-tile barrier
    if (kt < 15) {
      const __hip_bfloat16* ktile = kbase + (size_t)(kt + 1) * 64 * 8;
#pragma unroll
      for (int i = 0; i < 5; ++i) {
        int kb = i * 2 + w;
        if (kb < NKB) gld_lds16(ktile + (size_t)kb * (NN * 8) + lane * 8, &Ks[1 - cur][kb * 64 * 8]);
      }
    }

    // ---- S = Q K^T for both row-groups; each K fragment load feeds 2 MFMAs
    f32x4 s[2][4] = {};
#pragma unroll
    for (int ks = 0; ks < 3; ++ks) {
      const __hip_bfloat16* kbL = (ks < 2 || fq == 0) ? &Ks[cur][(ks * 4 + fq) * 512] : Zs;
#pragma unroll
      for (int tn = 0; tn < 4; ++tn) {
        bf16x8 kb = *(const bf16x8*)&kbL[(tn * 16 + fr) * 8];
        s[0][tn] = __builtin_amdgcn_mfma_f32_16x16x32_bf16(qa[0][ks], kb, s[0][tn], 0, 0, 0);
        s[1][tn] = __builtin_amdgcn_mfma_f32_16x16x32_bf16(qa[1][ks], kb, s[1][tn], 0, 0, 0);
      }
    }
    // ---- no-max softmax: p = exp2(s) (log2e pre-folded into K); per-lane partial row sums
#pragma unroll
    for (int g = 0; g < 2; ++g) {
      __hip_bfloat16* Pw = &Qs[(w * 2 + g) * 1152];  // 16x72 per-wave-group region
#pragma unroll
      for (int tn = 0; tn < 4; ++tn)
#pragma unroll
        for (int r = 0; r < 4; ++r) {
          float pe = __builtin_amdgcn_exp2f(s[g][tn][r]);
          l_part[g][r] += pe;
          Pw[(fq * 4 + r) * 72 + tn * 16 + fr] = __float2bfloat16(pe);
        }
    }
    // ---- O += P V; V fragments from registers
#pragma unroll
    for (int ks2 = 0; ks2 < 2; ++ks2) {
      bf16x8 pa0 = *(const bf16x8*)&Qs[(w * 2 + 0) * 1152 + fr * 72 + ks2 * 32 + fq * 8];
      bf16x8 pa1 = *(const bf16x8*)&Qs[(w * 2 + 1) * 1152 + fr * 72 + ks2 * 32 + fq * 8];
#pragma unroll
      for (int tv = 0; tv < 5; ++tv) {
        o_acc[0][tv] = __builtin_amdgcn_mfma_f32_16x16x32_bf16(pa0, vfrag[tv][ks2], o_acc[0][tv], 0, 0, 0);
        o_acc[1][tv] = __builtin_amdgcn_mfma_f32_16x16x32_bf16(pa1, vfrag[tv][ks2], o_acc[1][tv], 0, 0, 0);
      }
    }
    __syncthreads();  // end of tile: Ks[cur]/Ps reads done; drains kt+1 prefetch (hidden)
  }
  // ---- epilogue: reduce l across the 16 row-lanes (4 shfls, once), O / l -> bf16
#pragma unroll
  for (int g = 0; g < 2; ++g) {
    __hip_bfloat16* obase = Ao + (size_t)(b * NN + qt * AQR + w * 32 + g * 16) * CC + h * HD;
    float inv[4];
#pragma unroll
    for (int r = 0; r < 4; ++r) {
      float l = l_part[g][r];
#pragma unroll
      for (int msk = 8; msk >= 1; msk >>= 1) l += __shfl_xor(l, msk);
      inv[r] = 1.f / l;
    }
#pragma unroll
    for (int tv = 0; tv < 5; ++tv) {
      int d = tv * 16 + fr;
      if (d < HD) {
#pragma unroll
        for (int r = 0; r < 4; ++r)
          obase[(size_t)(fq * 4 + r) * CC + d] = __float2bfloat16(o_acc[g][tv][r] * inv[r]);
      }
    }
  }
}

// ---------------------------------------------------------------- launch
extern "C" void kernel_launch(void* const* d_in, const int* in_sizes, int n_in,
                              void* d_out, int out_size, void* d_ws, size_t ws_size,
                              hipStream_t stream) {
  (void)in_sizes; (void)n_in; (void)out_size; (void)ws_size;
  const float* x       = (const float*)d_in[0];
  const float* norm_g  = (const float*)d_in[1];
  const float* norm_b  = (const float*)d_in[2];
  const float* ap_w    = (const float*)d_in[3];
  const float* ap_b    = (const float*)d_in[4];
  const float* norm2_g = (const float*)d_in[5];
  const float* norm2_b = (const float*)d_in[6];
  const float* qkv_w   = (const float*)d_in[7];
  const float* proj_w  = (const float*)d_in[8];
  const float* proj_b  = (const float*)d_in[9];
  const float* sf      = (const float*)d_in[10];
  float* out = (float*)d_out;
  char* ws = (char*)d_ws;

  // workspace layout (bytes) — 57.6MB total (qp/kp: 9 kblk k-major slabs)
  __hip_bfloat16* xr   = (__hip_bfloat16*)(ws);                // 8192*544*2  = 8912896
  float* scores        = (float*)(ws + 8912896);               // 8192*17*4   = 557056
  float2* tab          = (float2*)(ws + 9469952);              // 136*8 -> pad 4096
  __hip_bfloat16* xp   = (__hip_bfloat16*)(ws + 9474048);      // 8912896
  __hip_bfloat16* qw   = (__hip_bfloat16*)(ws + 18386944);     // 1664*544*2  = 1810432
  __hip_bfloat16* pw   = (__hip_bfloat16*)(ws + 20197376);     // 640*544*2   = 696320
  __hip_bfloat16* vt   = (__hip_bfloat16*)(ws + 20893696);     // 8*8*68*1024*2 = 8912896
  __hip_bfloat16* ao   = (__hip_bfloat16*)(ws + 29806592);     // 8912896
  __hip_bfloat16* qp   = (__hip_bfloat16*)(ws + 38719488);     // 64*73728*2 = 9437184
  __hip_bfloat16* kp   = (__hip_bfloat16*)(ws + 48156672);     // 9437184
  // total 57593856 bytes

  wconv_ln1<<<BN / 4 + NCQP + NCPP, 256, 0, stream>>>(
      x, norm_g, norm_b, ap_w, ap_b, xr, scores, qkv_w, proj_w, qw, pw);
  softmax_red<<<BB * JJ, 256, 0, stream>>>(scores, tab);
  ln2_xp<<<BN / 4, 256, 0, stream>>>(xr, scores, tab, norm2_g, norm2_b, xp);
  gemm_nt<0><<<dim3(64 * 13), 256, 34816, stream>>>(xp, qw, qp, kp, vt, nullptr, nullptr, sf);
  attn_kernel<<<dim3((NN / AQR) * HH * BB), 128, 0, stream>>>(qp, kp, vt, ao);
  gemm_nt<1><<<dim3(64 * 5), 256, 34816, stream>>>(ao, pw, nullptr, nullptr, nullptr, out, proj_b, nullptr);
}